// Round 7
// baseline (208.358 us; speedup 1.0000x reference)
//
#include <hip/hip_runtime.h>
#include <math.h>

// TransformerBlock N=2048, D=1024, H=16, DK=DV=64, FF=4096.
// Round 7: split-KV flash attention (chunks of 8 kv-tiles, grid (32,16,4),
// early-exit empty chunks -> ~5 blocks/CU, 20 waves/CU) + combine kernel.
// GEMMs / LN unchanged.

#define NTOK   2048
#define DMODEL 1024
#define NHEAD  16
#define DHEAD  64
#define DFF    4096
#define LNEPS  1e-5f

typedef unsigned int   u32;
typedef unsigned short u16;
typedef __attribute__((ext_vector_type(8))) short short8;
typedef __attribute__((ext_vector_type(4))) float f32x4;

__device__ __forceinline__ u16 f2b(float f) {
    u32 b = __float_as_uint(f);
    b += 0x7FFFu + ((b >> 16) & 1u);   // RNE
    return (u16)(b >> 16);
}
__device__ __forceinline__ float b2f(u16 v) {
    return __uint_as_float((u32)v << 16);
}

#define AS1(p) ((const __attribute__((address_space(1))) u32*)(p))
#define AS3(p) ((__attribute__((address_space(3))) u32*)(p))

// ---------------- bf16 MFMA GEMM, 128x128 tile, BK=32, 2-phase dbuf --------
template<int RELU, int BIAS, int RESID, int OUT_BF16, int SPLITK>
__global__ __launch_bounds__(256) void mfma_gemm(
    const u16* __restrict__ A, int lda,
    const u16* __restrict__ Bt, int ldbt,
    void* __restrict__ Cp, int ldc, int Kc,
    const float* __restrict__ bias,
    const float* __restrict__ resid, int ldr,
    size_t pstride)
{
    __shared__ u16 As[2][128 * 32];
    __shared__ u16 Bs[2][128 * 32];

    const int tid = threadIdx.x;
    const int l = tid & 63, w = tid >> 6;
    const int row0 = blockIdx.y * 128, col0 = blockIdx.x * 128;
    const int kbase = (SPLITK > 1) ? blockIdx.z * Kc : 0;

    f32x4 acc[4][4];
    #pragma unroll
    for (int m = 0; m < 4; ++m)
        #pragma unroll
        for (int n = 0; n < 4; ++n)
            acc[m][n] = (f32x4){0.f, 0.f, 0.f, 0.f};

    const int srow = w * 32 + (l >> 2);
    const int skk  = (l & 3) * 8;
    const u16* Ag = A  + (size_t)(row0 + srow) * lda  + kbase + skk;
    const u16* Bg = Bt + (size_t)(col0 + srow) * ldbt + kbase + skk;

    const int fr  = l & 15;
    const int fk  = (l >> 4) * 8;
    const int ar0 = (w >> 1) * 64;
    const int bc0 = (w & 1) * 64;

    auto STAGE = [&](int buf, int k0) {
        char* AsB = (char*)&As[buf][0] + w * 2048;
        char* BsB = (char*)&Bs[buf][0] + w * 2048;
        __builtin_amdgcn_global_load_lds(AS1(Ag + k0),                     AS3(AsB),        16, 0, 0);
        __builtin_amdgcn_global_load_lds(AS1(Ag + k0 + (size_t)16 * lda),  AS3(AsB + 1024), 16, 0, 0);
        __builtin_amdgcn_global_load_lds(AS1(Bg + k0),                     AS3(BsB),        16, 0, 0);
        __builtin_amdgcn_global_load_lds(AS1(Bg + k0 + (size_t)16 * ldbt), AS3(BsB + 1024), 16, 0, 0);
    };

    STAGE(0, 0);
    int cur = 0;
    for (int k0 = 0; k0 < Kc; k0 += 32) {
        __syncthreads();
        if (k0 + 32 < Kc) STAGE(cur ^ 1, k0 + 32);

        short8 af[4], bfr[4];
        #pragma unroll
        for (int m = 0; m < 4; ++m)
            af[m] = *reinterpret_cast<const short8*>(&As[cur][(ar0 + m * 16 + fr) * 32 + fk]);
        #pragma unroll
        for (int n = 0; n < 4; ++n)
            bfr[n] = *reinterpret_cast<const short8*>(&Bs[cur][(bc0 + n * 16 + fr) * 32 + fk]);
        #pragma unroll
        for (int m = 0; m < 4; ++m)
            #pragma unroll
            for (int n = 0; n < 4; ++n)
                acc[m][n] = __builtin_amdgcn_mfma_f32_16x16x32_bf16(af[m], bfr[n], acc[m][n], 0, 0, 0);
        cur ^= 1;
    }

    if (SPLITK > 1) {
        float* Pp = (float*)Cp + blockIdx.z * pstride;
        #pragma unroll
        for (int m = 0; m < 4; ++m)
            #pragma unroll
            for (int n = 0; n < 4; ++n)
                #pragma unroll
                for (int r = 0; r < 4; ++r) {
                    int row = row0 + ar0 + m * 16 + (l >> 4) * 4 + r;
                    int col = col0 + bc0 + n * 16 + (l & 15);
                    Pp[(size_t)row * ldc + col] = acc[m][n][r];
                }
        return;
    }

    #pragma unroll
    for (int m = 0; m < 4; ++m) {
        #pragma unroll
        for (int n = 0; n < 4; ++n) {
            #pragma unroll
            for (int r = 0; r < 4; ++r) {
                int row = row0 + ar0 + m * 16 + (l >> 4) * 4 + r;
                int col = col0 + bc0 + n * 16 + (l & 15);
                float val = acc[m][n][r];
                if (BIAS)  val += bias[col];
                if (RESID) val += resid[(size_t)row * ldr + col];
                if (RELU)  val = fmaxf(val, 0.0f);
                if (OUT_BF16) ((u16*)Cp)[(size_t)row * ldc + col] = f2b(val);
                else          ((float*)Cp)[(size_t)row * ldc + col] = val;
            }
        }
    }
}

// ---------------- cast / transpose helpers ----------------
__global__ __launch_bounds__(256) void cast_f32_bf16(const float* __restrict__ in,
                                                     u16* __restrict__ out, int n)
{
    int i = (blockIdx.x * 256 + threadIdx.x) * 4;
    if (i + 3 < n) {
        float4 v = *reinterpret_cast<const float4*>(in + i);
        ushort4 o;
        o.x = f2b(v.x); o.y = f2b(v.y); o.z = f2b(v.z); o.w = f2b(v.w);
        *reinterpret_cast<ushort4*>(out + i) = o;
    }
}

__device__ __forceinline__ void transpose_body(const float* __restrict__ in, int ldin,
                                               u16* __restrict__ out, int ldout)
{
    __shared__ float tile[32][33];
    int r0 = blockIdx.y * 32, c0 = blockIdx.x * 32;
    int tx = threadIdx.x & 31, ty = threadIdx.x >> 5;
    #pragma unroll
    for (int i = 0; i < 4; ++i) {
        int r = ty + i * 8;
        tile[r][tx] = in[(size_t)(r0 + r) * ldin + c0 + tx];
    }
    __syncthreads();
    #pragma unroll
    for (int i = 0; i < 4; ++i) {
        int rr = ty + i * 8;
        out[(size_t)(c0 + rr) * ldout + r0 + tx] = f2b(tile[tx][rr]);
    }
}

__global__ __launch_bounds__(256) void transpose_cast(const float* __restrict__ in, int ldin,
                                                      u16* __restrict__ out, int ldout)
{
    transpose_body(in, ldin, out, ldout);
}

__global__ __launch_bounds__(256) void cast_wqkv(
    const float* __restrict__ wq, const float* __restrict__ wk, const float* __restrict__ wv,
    u16* __restrict__ outT)
{
    int z = blockIdx.z, p = z >> 4, h = z & 15;
    const float* in = (p == 0 ? wq : p == 1 ? wk : wv) + (size_t)h * DMODEL * DHEAD;
    u16* out = outT + (size_t)(p * 1024 + h * 64) * DMODEL;
    transpose_body(in, DHEAD, out, DMODEL);
}

// ---------------- split-KV MFMA flash attention ----------------
// grid (32, 16, 4): it, h, chunk. Chunk c covers jt in [8c, min(8c+7, it)].
// it<=7: single chunk -> normalized bf16 write to concat. Else: unnormalized
// bf16 O_c + per-row m/l (fp32) to workspace; flash_combine merges.
__global__ __launch_bounds__(256) void flash_attn_mfma(
    const u16* __restrict__ qkvb, u16* __restrict__ concatb,
    u16* __restrict__ Oc, float* __restrict__ Ml, float* __restrict__ Ll)
{
    const int it = blockIdx.x, h = blockIdx.y, c = blockIdx.z;
    if ((c << 3) > it) return;
    const int jt_lo = c << 3;
    const int jt_hi = min(jt_lo + 7, it);

    const u16* qh = qkvb + h * DHEAD;
    const u16* kh = qkvb + DMODEL + h * DHEAD;
    const u16* vh = qkvb + 2 * DMODEL + h * DHEAD;
    const int LDQ = 3 * DMODEL;

    __shared__ u16 Ks[64][72];       // K rows (pad-72)
    __shared__ u16 Vt[64][72];       // V^T, k-blocks XOR-swizzled by (dv>>3)&7
    __shared__ u16 Ps[4][16][72];    // per-wave P tile

    const int tid = threadIdx.x;
    const int l = tid & 63, w = tid >> 6;
    const int fr = l & 15, fg = l >> 4;

    short8 qf[2];
    {
        const u16* qp = qh + (size_t)(it * 64 + w * 16 + fr) * LDQ + fg * 8;
        qf[0] = *reinterpret_cast<const short8*>(qp);
        qf[1] = *reinterpret_cast<const short8*>(qp + 32);
    }

    const int kr = tid >> 2, kc = (tid & 3) * 16;
    const int vp = tid >> 3, vc = (tid & 7) * 8;
    char* VtB = (char*)Vt;

    short8 kf0, kf1, vf0, vf1;
    auto PREFETCH = [&](int jt) {
        const u16* kg = kh + (size_t)(jt * 64 + kr) * LDQ + kc;
        kf0 = *reinterpret_cast<const short8*>(kg);
        kf1 = *reinterpret_cast<const short8*>(kg + 8);
        const u16* vg = vh + (size_t)(jt * 64 + 2 * vp) * LDQ + vc;
        vf0 = *reinterpret_cast<const short8*>(vg);
        vf1 = *reinterpret_cast<const short8*>(vg + LDQ);
    };

    f32x4 o[4];
    #pragma unroll
    for (int n = 0; n < 4; ++n) o[n] = (f32x4){0.f, 0.f, 0.f, 0.f};
    float m_run[4], l_run[4];
    #pragma unroll
    for (int r = 0; r < 4; ++r) { m_run[r] = -INFINITY; l_run[r] = 0.0f; }

    PREFETCH(jt_lo);

    for (int jt = jt_lo; jt <= jt_hi; ++jt) {
        __syncthreads();
        *reinterpret_cast<short8*>(&Ks[kr][kc])     = kf0;
        *reinterpret_cast<short8*>(&Ks[kr][kc + 8]) = kf1;
        #pragma unroll
        for (int i = 0; i < 8; ++i) {
            u32 word = (u32)(u16)vf0[i] | ((u32)(u16)vf1[i] << 16);
            int dv = vc + i;
            int off = 144 * dv + 16 * ((vp >> 2) ^ ((dv >> 3) & 7)) + 4 * (vp & 3);
            *reinterpret_cast<u32*>(VtB + off) = word;
        }
        if (jt < jt_hi) PREFETCH(jt + 1);
        __syncthreads();

        f32x4 s[4];
        #pragma unroll
        for (int n = 0; n < 4; ++n) s[n] = (f32x4){0.f, 0.f, 0.f, 0.f};
        __builtin_amdgcn_s_setprio(1);
        #pragma unroll
        for (int n = 0; n < 4; ++n) {
            #pragma unroll
            for (int ks = 0; ks < 2; ++ks) {
                short8 bfK = *reinterpret_cast<const short8*>(&Ks[n * 16 + fr][ks * 32 + fg * 8]);
                s[n] = __builtin_amdgcn_mfma_f32_16x16x32_bf16(qf[ks], bfK, s[n], 0, 0, 0);
            }
        }
        __builtin_amdgcn_s_setprio(0);

        const bool diag = (jt == it);
        #pragma unroll
        for (int r = 0; r < 4; ++r) {
            int qrow = w * 16 + fg * 4 + r;
            float sv[4];
            float pm = -INFINITY;
            #pragma unroll
            for (int n = 0; n < 4; ++n) {
                float vsc = s[n][r] * 0.125f;
                if (diag && (n * 16 + fr) > qrow) vsc = -INFINITY;
                sv[n] = vsc;
                pm = fmaxf(pm, vsc);
            }
            pm = fmaxf(pm, __shfl_xor(pm, 1));
            pm = fmaxf(pm, __shfl_xor(pm, 2));
            pm = fmaxf(pm, __shfl_xor(pm, 4));
            pm = fmaxf(pm, __shfl_xor(pm, 8));
            float mnew = fmaxf(m_run[r], pm);
            float corr = __expf(m_run[r] - mnew);
            float rs = 0.0f;
            #pragma unroll
            for (int n = 0; n < 4; ++n) {
                float pv = __expf(sv[n] - mnew);
                rs += pv;
                Ps[w][fg * 4 + r][n * 16 + fr] = f2b(pv);
            }
            rs += __shfl_xor(rs, 1);
            rs += __shfl_xor(rs, 2);
            rs += __shfl_xor(rs, 4);
            rs += __shfl_xor(rs, 8);
            l_run[r] = l_run[r] * corr + rs;
            m_run[r] = mnew;
            #pragma unroll
            for (int n = 0; n < 4; ++n) o[n][r] *= corr;
        }

        __builtin_amdgcn_s_setprio(1);
        #pragma unroll
        for (int ks = 0; ks < 2; ++ks) {
            short8 pa = *reinterpret_cast<const short8*>(&Ps[w][fr][ks * 32 + fg * 8]);
            #pragma unroll
            for (int n = 0; n < 4; ++n) {
                int dv = n * 16 + fr;
                const short8* vbp = reinterpret_cast<const short8*>(
                    VtB + 144 * dv + 16 * ((ks * 4 + fg) ^ ((dv >> 3) & 7)));
                o[n] = __builtin_amdgcn_mfma_f32_16x16x32_bf16(pa, *vbp, o[n], 0, 0, 0);
            }
        }
        __builtin_amdgcn_s_setprio(0);
    }

    if (it <= 7) {
        // single chunk: normalized output straight to concat
        #pragma unroll
        for (int r = 0; r < 4; ++r) {
            float inv = 1.0f / l_run[r];
            int qrow = it * 64 + w * 16 + fg * 4 + r;
            #pragma unroll
            for (int n = 0; n < 4; ++n)
                concatb[(size_t)qrow * DMODEL + h * DHEAD + n * 16 + fr] = f2b(o[n][r] * inv);
        }
    } else {
        // partial: unnormalized O_c + m/l
        #pragma unroll
        for (int r = 0; r < 4; ++r) {
            int qrow = it * 64 + w * 16 + fg * 4 + r;
            size_t base = ((size_t)(c * NHEAD + h) * NTOK + qrow) * DHEAD;
            #pragma unroll
            for (int n = 0; n < 4; ++n)
                Oc[base + n * 16 + fr] = f2b(o[n][r]);
            if (fr == 0) {
                size_t mi = (size_t)(c * NHEAD + h) * NTOK + qrow;
                Ml[mi] = m_run[r];
                Ll[mi] = l_run[r];
            }
        }
    }
}

// ---------------- flash combine: merge per-chunk partials ----------------
// wave task: (h, row) for rows 512..2047. 64 lanes = 64 dv cols.
__global__ __launch_bounds__(256) void flash_combine(
    const u16* __restrict__ Oc, const float* __restrict__ Ml, const float* __restrict__ Ll,
    u16* __restrict__ concatb)
{
    int task = blockIdx.x * 4 + (threadIdx.x >> 6);
    int lane = threadIdx.x & 63;
    int h = task / 1536;
    int row = 512 + task % 1536;
    int it = row >> 6;
    int nch = (it >> 3) + 1;

    float mstar = -INFINITY;
    #pragma unroll
    for (int c = 0; c < 4; ++c)
        if (c < nch) mstar = fmaxf(mstar, Ml[(size_t)(c * NHEAD + h) * NTOK + row]);

    float lsum = 0.0f, acc = 0.0f;
    #pragma unroll
    for (int c = 0; c < 4; ++c) {
        if (c < nch) {
            size_t mi = (size_t)(c * NHEAD + h) * NTOK + row;
            float sc = __expf(Ml[mi] - mstar);
            lsum += sc * Ll[mi];
            acc  += sc * b2f(Oc[mi * DHEAD + lane]);
        }
    }
    concatb[(size_t)row * DMODEL + h * DHEAD + lane] = f2b(acc / lsum);
}

// ---------------- fused partial-reduce + LayerNorm ----------------
template<int NPART, int RELUB, int DUAL>
__global__ __launch_bounds__(256) void ln_fuse(
    const float* __restrict__ P, size_t pstride,
    const float* __restrict__ base,
    const float* __restrict__ bias2,
    const float* __restrict__ g, const float* __restrict__ b,
    float* __restrict__ out, u16* __restrict__ outb)
{
    int row = blockIdx.x, tid = threadIdx.x;
    __shared__ float red[256];
    size_t off = (size_t)row * DMODEL + tid * 4;

    float4 acc = *reinterpret_cast<const float4*>(P + off);
    #pragma unroll
    for (int p = 1; p < NPART; ++p) {
        float4 t = *reinterpret_cast<const float4*>(P + (size_t)p * pstride + off);
        acc.x += t.x; acc.y += t.y; acc.z += t.z; acc.w += t.w;
    }
    if (RELUB) {
        float4 bb = *reinterpret_cast<const float4*>(bias2 + tid * 4);
        acc.x = fmaxf(acc.x + bb.x, 0.0f); acc.y = fmaxf(acc.y + bb.y, 0.0f);
        acc.z = fmaxf(acc.z + bb.z, 0.0f); acc.w = fmaxf(acc.w + bb.w, 0.0f);
    }
    float4 bs = *reinterpret_cast<const float4*>(base + off);
    float vals[4] = {acc.x + bs.x, acc.y + bs.y, acc.z + bs.z, acc.w + bs.w};

    float s = vals[0] + vals[1] + vals[2] + vals[3];
    red[tid] = s; __syncthreads();
    for (int st = 128; st > 0; st >>= 1) { if (tid < st) red[tid] += red[tid + st]; __syncthreads(); }
    float mu = red[0] * (1.0f / DMODEL);
    __syncthreads();

    float vs = 0.0f;
    #pragma unroll
    for (int i = 0; i < 4; ++i) { float d = vals[i] - mu; vs += d * d; }
    red[tid] = vs; __syncthreads();
    for (int st = 128; st > 0; st >>= 1) { if (tid < st) red[tid] += red[tid + st]; __syncthreads(); }
    float rstd = rsqrtf(red[0] * (1.0f / DMODEL) + LNEPS);

    float4 gv = *reinterpret_cast<const float4*>(g + tid * 4);
    float4 bv = *reinterpret_cast<const float4*>(b + tid * 4);
    float gs[4] = {gv.x, gv.y, gv.z, gv.w};
    float bsc[4] = {bv.x, bv.y, bv.z, bv.w};
    #pragma unroll
    for (int i = 0; i < 4; ++i) {
        float r = (vals[i] - mu) * rstd * gs[i] + bsc[i];
        out[off + i] = r;
        if (DUAL) outb[off + i] = f2b(r);
    }
}

// ---------------- launch ----------------
extern "C" void kernel_launch(void* const* d_in, const int* in_sizes, int n_in,
                              void* d_out, int out_size, void* d_ws, size_t ws_size,
                              hipStream_t stream)
{
    const float* x    = (const float*)d_in[0];
    const float* wq   = (const float*)d_in[1];
    const float* wk   = (const float*)d_in[2];
    const float* wv   = (const float*)d_in[3];
    const float* wo   = (const float*)d_in[4];
    const float* ln1g = (const float*)d_in[5];
    const float* ln1b = (const float*)d_in[6];
    const float* w1   = (const float*)d_in[7];
    const float* b1   = (const float*)d_in[8];
    const float* w2   = (const float*)d_in[9];
    const float* b2   = (const float*)d_in[10];
    const float* ln2g = (const float*)d_in[11];
    const float* ln2b = (const float*)d_in[12];
    float* out = (float*)d_out;

    // 64 MB workspace, time-sliced (liveness-checked):
    //  [0,8)    w2T                      (cast -> ffn2)
    //  [8,14)   wqkvT (cast -> qkv)      then Oc [8,24) (flash -> combine)
    //           then P01 [8,24) (oproj -> LN1), then ff1b [8,24) (ffn1 -> ffn2)
    //  [24,25)  Ml/Ll (flash -> combine) then part of FP
    //  [24,56)  FP ffn2 partials x4      (ffn2 -> LN2)
    //  [26,28)  woT                      (cast -> oproj)
    //  [28,32)  h1b                      (LN1 -> ffn1)
    //  [40,48)  w1T                      (cast -> ffn1)
    //  [48,52)  xb (cast -> qkv)         then concatb (flash/combine -> oproj)
    //  [52,64)  qkvb (qkv -> flash)
    //  [56,64)  h1                       (LN1 -> LN2)
    char* ws = (char*)d_ws;
    const size_t MB = 1024 * 1024;
    u16*   w2T     = (u16*)  (ws + 0 * MB);
    u16*   wqkvT   = (u16*)  (ws + 8 * MB);
    u16*   Oc      = (u16*)  (ws + 8 * MB);          // 16 MB [4][16][2048][64] bf16
    float* P01     = (float*)(ws + 8 * MB);          // 2 x 8 MB
    u16*   ff1b    = (u16*)  (ws + 8 * MB);          // 16 MB
    float* Ml      = (float*)(ws + 24 * MB);         // 512 KB
    float* Ll      = (float*)(ws + 24 * MB + 512 * 1024);
    float* FP      = (float*)(ws + 24 * MB);         // 4 x 8 MB (ffn2 partials)
    u16*   woT     = (u16*)  (ws + 26 * MB);
    u16*   h1b     = (u16*)  (ws + 28 * MB);
    u16*   w1T     = (u16*)  (ws + 40 * MB);
    u16*   xb      = (u16*)  (ws + 48 * MB);
    u16*   concatb = (u16*)  (ws + 48 * MB);
    u16*   qkvb    = (u16*)  (ws + 52 * MB);
    float* h1      = (float*)(ws + 56 * MB);

    const size_t PSTRIDE = (size_t)NTOK * DMODEL;

    dim3 blk(256);

    cast_f32_bf16<<<dim3(NTOK * DMODEL / 1024), blk, 0, stream>>>(x, xb, NTOK * DMODEL);
    cast_wqkv<<<dim3(2, 32, 48), blk, 0, stream>>>(wq, wk, wv, wqkvT);
    transpose_cast<<<dim3(32, 32),  blk, 0, stream>>>(wo, DMODEL, woT, DMODEL);
    transpose_cast<<<dim3(128, 32), blk, 0, stream>>>(w1, DFF, w1T, DMODEL);
    transpose_cast<<<dim3(32, 128), blk, 0, stream>>>(w2, DMODEL, w2T, DFF);

    mfma_gemm<0,0,0,1,1><<<dim3(24, 16), blk, 0, stream>>>(
        xb, DMODEL, wqkvT, DMODEL, qkvb, 3 * DMODEL, DMODEL, nullptr, nullptr, 0, 0);
    flash_attn_mfma<<<dim3(32, 16, 4), blk, 0, stream>>>(qkvb, concatb, Oc, Ml, Ll);
    flash_combine<<<dim3(6144), blk, 0, stream>>>(Oc, Ml, Ll, concatb);
    mfma_gemm<0,0,0,0,2><<<dim3(8, 16, 2), blk, 0, stream>>>(
        concatb, DMODEL, woT, DMODEL, P01, DMODEL, 512, nullptr, nullptr, 0, PSTRIDE);
    ln_fuse<2,0,1><<<dim3(NTOK), blk, 0, stream>>>(
        P01, PSTRIDE, x, nullptr, ln1g, ln1b, h1, h1b);
    mfma_gemm<1,1,0,1,1><<<dim3(32, 16), blk, 0, stream>>>(
        h1b, DMODEL, w1T, DMODEL, ff1b, DFF, DMODEL, b1, nullptr, 0, 0);
    mfma_gemm<0,0,0,0,4><<<dim3(8, 16, 4), blk, 0, stream>>>(
        ff1b, DFF, w2T, DFF, FP, DMODEL, 1024, nullptr, nullptr, 0, PSTRIDE);
    ln_fuse<4,1,0><<<dim3(NTOK), blk, 0, stream>>>(
        FP, PSTRIDE, h1, b2, ln2g, ln2b, out, nullptr);
}

// Round 8
// 185.642 us; speedup vs baseline: 1.1224x; 1.1224x over previous
//
#include <hip/hip_runtime.h>
#include <math.h>

// TransformerBlock N=2048, D=1024, H=16, DK=DV=64, FF=4096.
// Round 8: swapped-operand MFMA flash attention — QK^T as mfma(K,Q) and PV as
// mfma(Vt,P) so each lane owns one q-row (q = lane&15): in-register softmax
// (2+2 shfls vs 32), lane-scalar m/l, in-register P redistribution (16 shfl),
// no Ps LDS. Split-KV reverted (R7: occupancy +60%, time flat -> not the
// limiter). GEMMs/LN unchanged.

#define NTOK   2048
#define DMODEL 1024
#define NHEAD  16
#define DHEAD  64
#define DFF    4096
#define LNEPS  1e-5f

typedef unsigned int   u32;
typedef unsigned short u16;
typedef __attribute__((ext_vector_type(8))) short short8;
typedef __attribute__((ext_vector_type(4))) float f32x4;

__device__ __forceinline__ u16 f2b(float f) {
    u32 b = __float_as_uint(f);
    b += 0x7FFFu + ((b >> 16) & 1u);   // RNE
    return (u16)(b >> 16);
}

#define AS1(p) ((const __attribute__((address_space(1))) u32*)(p))
#define AS3(p) ((__attribute__((address_space(3))) u32*)(p))

// ---------------- bf16 MFMA GEMM, 128x128 tile, BK=32, 2-phase dbuf --------
template<int RELU, int BIAS, int RESID, int OUT_BF16, int SPLITK>
__global__ __launch_bounds__(256) void mfma_gemm(
    const u16* __restrict__ A, int lda,
    const u16* __restrict__ Bt, int ldbt,
    void* __restrict__ Cp, int ldc, int Kc,
    const float* __restrict__ bias,
    const float* __restrict__ resid, int ldr,
    size_t pstride)
{
    __shared__ u16 As[2][128 * 32];
    __shared__ u16 Bs[2][128 * 32];

    const int tid = threadIdx.x;
    const int l = tid & 63, w = tid >> 6;
    const int row0 = blockIdx.y * 128, col0 = blockIdx.x * 128;
    const int kbase = (SPLITK > 1) ? blockIdx.z * Kc : 0;

    f32x4 acc[4][4];
    #pragma unroll
    for (int m = 0; m < 4; ++m)
        #pragma unroll
        for (int n = 0; n < 4; ++n)
            acc[m][n] = (f32x4){0.f, 0.f, 0.f, 0.f};

    const int srow = w * 32 + (l >> 2);
    const int skk  = (l & 3) * 8;
    const u16* Ag = A  + (size_t)(row0 + srow) * lda  + kbase + skk;
    const u16* Bg = Bt + (size_t)(col0 + srow) * ldbt + kbase + skk;

    const int fr  = l & 15;
    const int fk  = (l >> 4) * 8;
    const int ar0 = (w >> 1) * 64;
    const int bc0 = (w & 1) * 64;

    auto STAGE = [&](int buf, int k0) {
        char* AsB = (char*)&As[buf][0] + w * 2048;
        char* BsB = (char*)&Bs[buf][0] + w * 2048;
        __builtin_amdgcn_global_load_lds(AS1(Ag + k0),                     AS3(AsB),        16, 0, 0);
        __builtin_amdgcn_global_load_lds(AS1(Ag + k0 + (size_t)16 * lda),  AS3(AsB + 1024), 16, 0, 0);
        __builtin_amdgcn_global_load_lds(AS1(Bg + k0),                     AS3(BsB),        16, 0, 0);
        __builtin_amdgcn_global_load_lds(AS1(Bg + k0 + (size_t)16 * ldbt), AS3(BsB + 1024), 16, 0, 0);
    };

    STAGE(0, 0);
    int cur = 0;
    for (int k0 = 0; k0 < Kc; k0 += 32) {
        __syncthreads();
        if (k0 + 32 < Kc) STAGE(cur ^ 1, k0 + 32);

        short8 af[4], bfr[4];
        #pragma unroll
        for (int m = 0; m < 4; ++m)
            af[m] = *reinterpret_cast<const short8*>(&As[cur][(ar0 + m * 16 + fr) * 32 + fk]);
        #pragma unroll
        for (int n = 0; n < 4; ++n)
            bfr[n] = *reinterpret_cast<const short8*>(&Bs[cur][(bc0 + n * 16 + fr) * 32 + fk]);
        #pragma unroll
        for (int m = 0; m < 4; ++m)
            #pragma unroll
            for (int n = 0; n < 4; ++n)
                acc[m][n] = __builtin_amdgcn_mfma_f32_16x16x32_bf16(af[m], bfr[n], acc[m][n], 0, 0, 0);
        cur ^= 1;
    }

    if (SPLITK > 1) {
        float* Pp = (float*)Cp + blockIdx.z * pstride;
        #pragma unroll
        for (int m = 0; m < 4; ++m)
            #pragma unroll
            for (int n = 0; n < 4; ++n)
                #pragma unroll
                for (int r = 0; r < 4; ++r) {
                    int row = row0 + ar0 + m * 16 + (l >> 4) * 4 + r;
                    int col = col0 + bc0 + n * 16 + (l & 15);
                    Pp[(size_t)row * ldc + col] = acc[m][n][r];
                }
        return;
    }

    #pragma unroll
    for (int m = 0; m < 4; ++m) {
        #pragma unroll
        for (int n = 0; n < 4; ++n) {
            #pragma unroll
            for (int r = 0; r < 4; ++r) {
                int row = row0 + ar0 + m * 16 + (l >> 4) * 4 + r;
                int col = col0 + bc0 + n * 16 + (l & 15);
                float val = acc[m][n][r];
                if (BIAS)  val += bias[col];
                if (RESID) val += resid[(size_t)row * ldr + col];
                if (RELU)  val = fmaxf(val, 0.0f);
                if (OUT_BF16) ((u16*)Cp)[(size_t)row * ldc + col] = f2b(val);
                else          ((float*)Cp)[(size_t)row * ldc + col] = val;
            }
        }
    }
}

// ---------------- cast / transpose helpers ----------------
__global__ __launch_bounds__(256) void cast_f32_bf16(const float* __restrict__ in,
                                                     u16* __restrict__ out, int n)
{
    int i = (blockIdx.x * 256 + threadIdx.x) * 4;
    if (i + 3 < n) {
        float4 v = *reinterpret_cast<const float4*>(in + i);
        ushort4 o;
        o.x = f2b(v.x); o.y = f2b(v.y); o.z = f2b(v.z); o.w = f2b(v.w);
        *reinterpret_cast<ushort4*>(out + i) = o;
    }
}

__device__ __forceinline__ void transpose_body(const float* __restrict__ in, int ldin,
                                               u16* __restrict__ out, int ldout)
{
    __shared__ float tile[32][33];
    int r0 = blockIdx.y * 32, c0 = blockIdx.x * 32;
    int tx = threadIdx.x & 31, ty = threadIdx.x >> 5;
    #pragma unroll
    for (int i = 0; i < 4; ++i) {
        int r = ty + i * 8;
        tile[r][tx] = in[(size_t)(r0 + r) * ldin + c0 + tx];
    }
    __syncthreads();
    #pragma unroll
    for (int i = 0; i < 4; ++i) {
        int rr = ty + i * 8;
        out[(size_t)(c0 + rr) * ldout + r0 + tx] = f2b(tile[tx][rr]);
    }
}

__global__ __launch_bounds__(256) void transpose_cast(const float* __restrict__ in, int ldin,
                                                      u16* __restrict__ out, int ldout)
{
    transpose_body(in, ldin, out, ldout);
}

__global__ __launch_bounds__(256) void cast_wqkv(
    const float* __restrict__ wq, const float* __restrict__ wk, const float* __restrict__ wv,
    u16* __restrict__ outT)
{
    int z = blockIdx.z, p = z >> 4, h = z & 15;
    const float* in = (p == 0 ? wq : p == 1 ? wk : wv) + (size_t)h * DMODEL * DHEAD;
    u16* out = outT + (size_t)(p * 1024 + h * 64) * DMODEL;
    transpose_body(in, DHEAD, out, DMODEL);
}

// ---------------- swapped-operand MFMA flash attention ----------------
// 512 blocks, complementary-pair remap (R6). Per wave: 16 q-rows.
// QK^T: s[n] = mfma(K_frag[n], Q_frag)  -> S[kv][q], lane owns q = l&15.
// PV:   o[n] = mfma(Vt_frag[n], P_frag) -> O[dv][q], same lane ownership.
__global__ __launch_bounds__(256) void flash_attn_mfma(
    const u16* __restrict__ qkvb, u16* __restrict__ concatb)
{
    const int bid = blockIdx.x;
    const int lo = bid & 255;
    int it = lo >> 3;
    int h  = lo & 7;
    if (bid >= 256) { it = 31 - it; h += 8; }

    const u16* qh = qkvb + h * DHEAD;
    const u16* kh = qkvb + DMODEL + h * DHEAD;
    const u16* vh = qkvb + 2 * DMODEL + h * DHEAD;
    const int LDQ = 3 * DMODEL;

    __shared__ u16 Ks[64][72];       // K rows (pad-72)
    __shared__ u16 Vt[64][72];       // V^T, k-blocks XOR-swizzled by (dv>>3)&7

    const int tid = threadIdx.x;
    const int l = tid & 63, w = tid >> 6;
    const int fr = l & 15, fg = l >> 4;       // fr = q (owned row), fg = group

    // Q fragment (B-operand): lane holds Q[q=fr][k = fg*8 .. +7], 2 k-steps
    short8 qf[2];
    {
        const u16* qp = qh + (size_t)(it * 64 + w * 16 + fr) * LDQ + fg * 8;
        qf[0] = *reinterpret_cast<const short8*>(qp);
        qf[1] = *reinterpret_cast<const short8*>(qp + 32);
    }

    const int kr = tid >> 2, kc = (tid & 3) * 16;
    const int vp = tid >> 3, vc = (tid & 7) * 8;
    char* VtB = (char*)Vt;

    short8 kf0, kf1, vf0, vf1;
    auto PREFETCH = [&](int jt) {
        const u16* kg = kh + (size_t)(jt * 64 + kr) * LDQ + kc;
        kf0 = *reinterpret_cast<const short8*>(kg);
        kf1 = *reinterpret_cast<const short8*>(kg + 8);
        const u16* vg = vh + (size_t)(jt * 64 + 2 * vp) * LDQ + vc;
        vf0 = *reinterpret_cast<const short8*>(vg);
        vf1 = *reinterpret_cast<const short8*>(vg + LDQ);
    };

    f32x4 o[4];
    #pragma unroll
    for (int n = 0; n < 4; ++n) o[n] = (f32x4){0.f, 0.f, 0.f, 0.f};
    float m_run = -INFINITY, l_run = 0.0f;    // lane-scalar: q = fr

    // P redistribution lanes: sA holds kv base, sB = sA+16 the next 4
    const int sA = fr + 16 * ((2 * fg) & 3);
    const int sB = sA + 16;
    const bool hi = (fg >= 2);

    PREFETCH(0);

    for (int jt = 0; jt <= it; ++jt) {
        __syncthreads();
        *reinterpret_cast<short8*>(&Ks[kr][kc])     = kf0;
        *reinterpret_cast<short8*>(&Ks[kr][kc + 8]) = kf1;
        #pragma unroll
        for (int i = 0; i < 8; ++i) {
            u32 word = (u32)(u16)vf0[i] | ((u32)(u16)vf1[i] << 16);
            int dv = vc + i;
            int off = 144 * dv + 16 * ((vp >> 2) ^ ((dv >> 3) & 7)) + 4 * (vp & 3);
            *reinterpret_cast<u32*>(VtB + off) = word;
        }
        if (jt < it) PREFETCH(jt + 1);
        __syncthreads();

        // S^T = K @ Q^T : s[n] holds S[kv = n*16 + fg*4 + r][q = fr]
        f32x4 s[4];
        #pragma unroll
        for (int n = 0; n < 4; ++n) s[n] = (f32x4){0.f, 0.f, 0.f, 0.f};
        __builtin_amdgcn_s_setprio(1);
        #pragma unroll
        for (int n = 0; n < 4; ++n) {
            #pragma unroll
            for (int ks = 0; ks < 2; ++ks) {
                short8 kfrag = *reinterpret_cast<const short8*>(&Ks[n * 16 + fr][ks * 32 + fg * 8]);
                s[n] = __builtin_amdgcn_mfma_f32_16x16x32_bf16(kfrag, qf[ks], s[n], 0, 0, 0);
            }
        }
        __builtin_amdgcn_s_setprio(0);

        // in-register online softmax over this lane's q-row
        const bool diag = (jt == it);
        const int qrow_t = w * 16 + fr;
        float sv[4][4];
        float pm = -INFINITY;
        #pragma unroll
        for (int n = 0; n < 4; ++n)
            #pragma unroll
            for (int r = 0; r < 4; ++r) {
                float v = s[n][r] * 0.125f;
                if (diag && (n * 16 + fg * 4 + r) > qrow_t) v = -INFINITY;
                sv[n][r] = v;
                pm = fmaxf(pm, v);
            }
        pm = fmaxf(pm, __shfl_xor(pm, 16));
        pm = fmaxf(pm, __shfl_xor(pm, 32));
        float mnew = fmaxf(m_run, pm);
        float corr = __expf(m_run - mnew);
        float rs = 0.0f;
        float pp[4][4];
        #pragma unroll
        for (int n = 0; n < 4; ++n)
            #pragma unroll
            for (int r = 0; r < 4; ++r) {
                float pv = __expf(sv[n][r] - mnew);
                pp[n][r] = pv;
                rs += pv;
            }
        rs += __shfl_xor(rs, 16);
        rs += __shfl_xor(rs, 32);
        l_run = l_run * corr + rs;
        m_run = mnew;
        #pragma unroll
        for (int n = 0; n < 4; ++n) {
            o[n][0] *= corr; o[n][1] *= corr; o[n][2] *= corr; o[n][3] *= corr;
        }

        // pack P to bf16 pairs: pk[n][0] = (kv n*16+fg*4+0,+1), pk[n][1] = (+2,+3)
        u32 pk[4][2];
        #pragma unroll
        for (int n = 0; n < 4; ++n) {
            pk[n][0] = (u32)f2b(pp[n][0]) | ((u32)f2b(pp[n][1]) << 16);
            pk[n][1] = (u32)f2b(pp[n][2]) | ((u32)f2b(pp[n][3]) << 16);
        }

        // PV with in-register P redistribution:
        // B-frag for k-step ks: lane needs P[kv = 32ks + 8fg .. +7][q=fr]
        //   = frag n=2ks+(fg>>1): words {pk[n][0],pk[n][1]}@sA, same @sB.
        __builtin_amdgcn_s_setprio(1);
        #pragma unroll
        for (int ks = 0; ks < 2; ++ks) {
            u32 a0 = __shfl(pk[2 * ks][0], sA);
            u32 a1 = __shfl(pk[2 * ks][1], sA);
            u32 a2 = __shfl(pk[2 * ks][0], sB);
            u32 a3 = __shfl(pk[2 * ks][1], sB);
            u32 b0 = __shfl(pk[2 * ks + 1][0], sA);
            u32 b1 = __shfl(pk[2 * ks + 1][1], sA);
            u32 b2 = __shfl(pk[2 * ks + 1][0], sB);
            u32 b3 = __shfl(pk[2 * ks + 1][1], sB);
            union { u32 u[4]; short8 s8; } pb;
            pb.u[0] = hi ? b0 : a0;
            pb.u[1] = hi ? b1 : a1;
            pb.u[2] = hi ? b2 : a2;
            pb.u[3] = hi ? b3 : a3;
            #pragma unroll
            for (int n = 0; n < 4; ++n) {
                int dv = n * 16 + fr;
                const short8* vfrag = reinterpret_cast<const short8*>(
                    VtB + 144 * dv + 16 * ((ks * 4 + fg) ^ ((dv >> 3) & 7)));
                o[n] = __builtin_amdgcn_mfma_f32_16x16x32_bf16(*vfrag, pb.s8, o[n], 0, 0, 0);
            }
        }
        __builtin_amdgcn_s_setprio(0);
    }

    // epilogue: O[dv = n*16 + fg*4 + r][q = fr], write concat[q][h*64+dv]
    float inv = 1.0f / l_run;
    int qrow = it * 64 + w * 16 + fr;
    #pragma unroll
    for (int n = 0; n < 4; ++n)
        #pragma unroll
        for (int r = 0; r < 4; ++r)
            concatb[(size_t)qrow * DMODEL + h * DHEAD + n * 16 + fg * 4 + r] = f2b(o[n][r] * inv);
}

// ---------------- fused partial-reduce + LayerNorm ----------------
template<int NPART, int RELUB, int DUAL>
__global__ __launch_bounds__(256) void ln_fuse(
    const float* __restrict__ P, size_t pstride,
    const float* __restrict__ base,
    const float* __restrict__ bias2,
    const float* __restrict__ g, const float* __restrict__ b,
    float* __restrict__ out, u16* __restrict__ outb)
{
    int row = blockIdx.x, tid = threadIdx.x;
    __shared__ float red[256];
    size_t off = (size_t)row * DMODEL + tid * 4;

    float4 acc = *reinterpret_cast<const float4*>(P + off);
    #pragma unroll
    for (int p = 1; p < NPART; ++p) {
        float4 t = *reinterpret_cast<const float4*>(P + (size_t)p * pstride + off);
        acc.x += t.x; acc.y += t.y; acc.z += t.z; acc.w += t.w;
    }
    if (RELUB) {
        float4 bb = *reinterpret_cast<const float4*>(bias2 + tid * 4);
        acc.x = fmaxf(acc.x + bb.x, 0.0f); acc.y = fmaxf(acc.y + bb.y, 0.0f);
        acc.z = fmaxf(acc.z + bb.z, 0.0f); acc.w = fmaxf(acc.w + bb.w, 0.0f);
    }
    float4 bs = *reinterpret_cast<const float4*>(base + off);
    float vals[4] = {acc.x + bs.x, acc.y + bs.y, acc.z + bs.z, acc.w + bs.w};

    float s = vals[0] + vals[1] + vals[2] + vals[3];
    red[tid] = s; __syncthreads();
    for (int st = 128; st > 0; st >>= 1) { if (tid < st) red[tid] += red[tid + st]; __syncthreads(); }
    float mu = red[0] * (1.0f / DMODEL);
    __syncthreads();

    float vs = 0.0f;
    #pragma unroll
    for (int i = 0; i < 4; ++i) { float d = vals[i] - mu; vs += d * d; }
    red[tid] = vs; __syncthreads();
    for (int st = 128; st > 0; st >>= 1) { if (tid < st) red[tid] += red[tid + st]; __syncthreads(); }
    float rstd = rsqrtf(red[0] * (1.0f / DMODEL) + LNEPS);

    float4 gv = *reinterpret_cast<const float4*>(g + tid * 4);
    float4 bv = *reinterpret_cast<const float4*>(b + tid * 4);
    float gs[4] = {gv.x, gv.y, gv.z, gv.w};
    float bsc[4] = {bv.x, bv.y, bv.z, bv.w};
    #pragma unroll
    for (int i = 0; i < 4; ++i) {
        float r = (vals[i] - mu) * rstd * gs[i] + bsc[i];
        out[off + i] = r;
        if (DUAL) outb[off + i] = f2b(r);
    }
}

// ---------------- launch ----------------
extern "C" void kernel_launch(void* const* d_in, const int* in_sizes, int n_in,
                              void* d_out, int out_size, void* d_ws, size_t ws_size,
                              hipStream_t stream)
{
    const float* x    = (const float*)d_in[0];
    const float* wq   = (const float*)d_in[1];
    const float* wk   = (const float*)d_in[2];
    const float* wv   = (const float*)d_in[3];
    const float* wo   = (const float*)d_in[4];
    const float* ln1g = (const float*)d_in[5];
    const float* ln1b = (const float*)d_in[6];
    const float* w1   = (const float*)d_in[7];
    const float* b1   = (const float*)d_in[8];
    const float* w2   = (const float*)d_in[9];
    const float* b2   = (const float*)d_in[10];
    const float* ln2g = (const float*)d_in[11];
    const float* ln2b = (const float*)d_in[12];
    float* out = (float*)d_out;

    char* ws = (char*)d_ws;
    const size_t MB = 1024 * 1024;
    u16*   w2T     = (u16*)  (ws + 0 * MB);
    float* h1      = (float*)(ws + 8 * MB);
    float* P01     = (float*)(ws + 16 * MB);  // 2 x 8 MB (oproj partials)
    u16*   ff1b    = (u16*)  (ws + 16 * MB);  // after LN1
    float* FP      = (float*)(ws + 32 * MB);  // 4 x 8 MB (ffn2 partials)
    u16*   wqkvT   = (u16*)  (ws + 32 * MB);
    u16*   woT     = (u16*)  (ws + 38 * MB);
    u16*   w1T     = (u16*)  (ws + 40 * MB);
    u16*   xb      = (u16*)  (ws + 48 * MB);
    u16*   concatb = (u16*)  (ws + 48 * MB);
    u16*   h1b     = (u16*)  (ws + 48 * MB);
    u16*   qkvb    = (u16*)  (ws + 52 * MB);

    const size_t PSTRIDE = (size_t)NTOK * DMODEL;

    dim3 blk(256);

    cast_f32_bf16<<<dim3(NTOK * DMODEL / 1024), blk, 0, stream>>>(x, xb, NTOK * DMODEL);
    cast_wqkv<<<dim3(2, 32, 48), blk, 0, stream>>>(wq, wk, wv, wqkvT);
    transpose_cast<<<dim3(32, 32),  blk, 0, stream>>>(wo, DMODEL, woT, DMODEL);
    transpose_cast<<<dim3(128, 32), blk, 0, stream>>>(w1, DFF, w1T, DMODEL);
    transpose_cast<<<dim3(32, 128), blk, 0, stream>>>(w2, DMODEL, w2T, DFF);

    mfma_gemm<0,0,0,1,1><<<dim3(24, 16), blk, 0, stream>>>(
        xb, DMODEL, wqkvT, DMODEL, qkvb, 3 * DMODEL, DMODEL, nullptr, nullptr, 0, 0);
    flash_attn_mfma<<<dim3(512), blk, 0, stream>>>(qkvb, concatb);
    mfma_gemm<0,0,0,0,2><<<dim3(8, 16, 2), blk, 0, stream>>>(
        concatb, DMODEL, woT, DMODEL, P01, DMODEL, 512, nullptr, nullptr, 0, PSTRIDE);
    ln_fuse<2,0,1><<<dim3(NTOK), blk, 0, stream>>>(
        P01, PSTRIDE, x, nullptr, ln1g, ln1b, h1, h1b);
    mfma_gemm<1,1,0,1,1><<<dim3(32, 16), blk, 0, stream>>>(
        h1b, DMODEL, w1T, DMODEL, ff1b, DFF, DMODEL, b1, nullptr, 0, 0);
    mfma_gemm<0,0,0,0,4><<<dim3(8, 16, 4), blk, 0, stream>>>(
        ff1b, DFF, w2T, DFF, FP, DMODEL, 1024, nullptr, nullptr, 0, PSTRIDE);
    ln_fuse<4,1,0><<<dim3(NTOK), blk, 0, stream>>>(
        FP, PSTRIDE, h1, b2, ln2g, ln2b, out, nullptr);
}

// Round 9
// 174.793 us; speedup vs baseline: 1.1920x; 1.0621x over previous
//
#include <hip/hip_runtime.h>
#include <math.h>

// TransformerBlock N=2048, D=1024, H=16, DK=DV=64, FF=4096.
// Round 9: flash attention -> 8-wave blocks with intra-block split-KV:
// waves 0-3 process even kv-tiles, waves 4-7 odd ones, LDS merge at end.
// Doubles per-SIMD wave concurrency during solo-block periods (R8 diagnosis:
// latency-bound at 1 wave/SIMD). Truncation P-pack. GEMMs/LN unchanged.

#define NTOK   2048
#define DMODEL 1024
#define NHEAD  16
#define DHEAD  64
#define DFF    4096
#define LNEPS  1e-5f

typedef unsigned int   u32;
typedef unsigned short u16;
typedef __attribute__((ext_vector_type(8))) short short8;
typedef __attribute__((ext_vector_type(4))) float f32x4;

__device__ __forceinline__ u16 f2b(float f) {
    u32 b = __float_as_uint(f);
    b += 0x7FFFu + ((b >> 16) & 1u);   // RNE
    return (u16)(b >> 16);
}

#define AS1(p) ((const __attribute__((address_space(1))) u32*)(p))
#define AS3(p) ((__attribute__((address_space(3))) u32*)(p))

// ---------------- bf16 MFMA GEMM, 128x128 tile, BK=32, 2-phase dbuf --------
template<int RELU, int BIAS, int RESID, int OUT_BF16, int SPLITK>
__global__ __launch_bounds__(256) void mfma_gemm(
    const u16* __restrict__ A, int lda,
    const u16* __restrict__ Bt, int ldbt,
    void* __restrict__ Cp, int ldc, int Kc,
    const float* __restrict__ bias,
    const float* __restrict__ resid, int ldr,
    size_t pstride)
{
    __shared__ u16 As[2][128 * 32];
    __shared__ u16 Bs[2][128 * 32];

    const int tid = threadIdx.x;
    const int l = tid & 63, w = tid >> 6;
    const int row0 = blockIdx.y * 128, col0 = blockIdx.x * 128;
    const int kbase = (SPLITK > 1) ? blockIdx.z * Kc : 0;

    f32x4 acc[4][4];
    #pragma unroll
    for (int m = 0; m < 4; ++m)
        #pragma unroll
        for (int n = 0; n < 4; ++n)
            acc[m][n] = (f32x4){0.f, 0.f, 0.f, 0.f};

    const int srow = w * 32 + (l >> 2);
    const int skk  = (l & 3) * 8;
    const u16* Ag = A  + (size_t)(row0 + srow) * lda  + kbase + skk;
    const u16* Bg = Bt + (size_t)(col0 + srow) * ldbt + kbase + skk;

    const int fr  = l & 15;
    const int fk  = (l >> 4) * 8;
    const int ar0 = (w >> 1) * 64;
    const int bc0 = (w & 1) * 64;

    auto STAGE = [&](int buf, int k0) {
        char* AsB = (char*)&As[buf][0] + w * 2048;
        char* BsB = (char*)&Bs[buf][0] + w * 2048;
        __builtin_amdgcn_global_load_lds(AS1(Ag + k0),                     AS3(AsB),        16, 0, 0);
        __builtin_amdgcn_global_load_lds(AS1(Ag + k0 + (size_t)16 * lda),  AS3(AsB + 1024), 16, 0, 0);
        __builtin_amdgcn_global_load_lds(AS1(Bg + k0),                     AS3(BsB),        16, 0, 0);
        __builtin_amdgcn_global_load_lds(AS1(Bg + k0 + (size_t)16 * ldbt), AS3(BsB + 1024), 16, 0, 0);
    };

    STAGE(0, 0);
    int cur = 0;
    for (int k0 = 0; k0 < Kc; k0 += 32) {
        __syncthreads();
        if (k0 + 32 < Kc) STAGE(cur ^ 1, k0 + 32);

        short8 af[4], bfr[4];
        #pragma unroll
        for (int m = 0; m < 4; ++m)
            af[m] = *reinterpret_cast<const short8*>(&As[cur][(ar0 + m * 16 + fr) * 32 + fk]);
        #pragma unroll
        for (int n = 0; n < 4; ++n)
            bfr[n] = *reinterpret_cast<const short8*>(&Bs[cur][(bc0 + n * 16 + fr) * 32 + fk]);
        #pragma unroll
        for (int m = 0; m < 4; ++m)
            #pragma unroll
            for (int n = 0; n < 4; ++n)
                acc[m][n] = __builtin_amdgcn_mfma_f32_16x16x32_bf16(af[m], bfr[n], acc[m][n], 0, 0, 0);
        cur ^= 1;
    }

    if (SPLITK > 1) {
        float* Pp = (float*)Cp + blockIdx.z * pstride;
        #pragma unroll
        for (int m = 0; m < 4; ++m)
            #pragma unroll
            for (int n = 0; n < 4; ++n)
                #pragma unroll
                for (int r = 0; r < 4; ++r) {
                    int row = row0 + ar0 + m * 16 + (l >> 4) * 4 + r;
                    int col = col0 + bc0 + n * 16 + (l & 15);
                    Pp[(size_t)row * ldc + col] = acc[m][n][r];
                }
        return;
    }

    #pragma unroll
    for (int m = 0; m < 4; ++m) {
        #pragma unroll
        for (int n = 0; n < 4; ++n) {
            #pragma unroll
            for (int r = 0; r < 4; ++r) {
                int row = row0 + ar0 + m * 16 + (l >> 4) * 4 + r;
                int col = col0 + bc0 + n * 16 + (l & 15);
                float val = acc[m][n][r];
                if (BIAS)  val += bias[col];
                if (RESID) val += resid[(size_t)row * ldr + col];
                if (RELU)  val = fmaxf(val, 0.0f);
                if (OUT_BF16) ((u16*)Cp)[(size_t)row * ldc + col] = f2b(val);
                else          ((float*)Cp)[(size_t)row * ldc + col] = val;
            }
        }
    }
}

// ---------------- cast / transpose helpers ----------------
__global__ __launch_bounds__(256) void cast_f32_bf16(const float* __restrict__ in,
                                                     u16* __restrict__ out, int n)
{
    int i = (blockIdx.x * 256 + threadIdx.x) * 4;
    if (i + 3 < n) {
        float4 v = *reinterpret_cast<const float4*>(in + i);
        ushort4 o;
        o.x = f2b(v.x); o.y = f2b(v.y); o.z = f2b(v.z); o.w = f2b(v.w);
        *reinterpret_cast<ushort4*>(out + i) = o;
    }
}

__device__ __forceinline__ void transpose_body(const float* __restrict__ in, int ldin,
                                               u16* __restrict__ out, int ldout)
{
    __shared__ float tile[32][33];
    int r0 = blockIdx.y * 32, c0 = blockIdx.x * 32;
    int tx = threadIdx.x & 31, ty = threadIdx.x >> 5;
    #pragma unroll
    for (int i = 0; i < 4; ++i) {
        int r = ty + i * 8;
        tile[r][tx] = in[(size_t)(r0 + r) * ldin + c0 + tx];
    }
    __syncthreads();
    #pragma unroll
    for (int i = 0; i < 4; ++i) {
        int rr = ty + i * 8;
        out[(size_t)(c0 + rr) * ldout + r0 + tx] = f2b(tile[tx][rr]);
    }
}

__global__ __launch_bounds__(256) void transpose_cast(const float* __restrict__ in, int ldin,
                                                      u16* __restrict__ out, int ldout)
{
    transpose_body(in, ldin, out, ldout);
}

__global__ __launch_bounds__(256) void cast_wqkv(
    const float* __restrict__ wq, const float* __restrict__ wk, const float* __restrict__ wv,
    u16* __restrict__ outT)
{
    int z = blockIdx.z, p = z >> 4, h = z & 15;
    const float* in = (p == 0 ? wq : p == 1 ? wk : wv) + (size_t)h * DMODEL * DHEAD;
    u16* out = outT + (size_t)(p * 1024 + h * 64) * DMODEL;
    transpose_body(in, DHEAD, out, DMODEL);
}

// ---------------- 8-wave split-KV swapped-operand flash attention ----------
// 512 blocks (pair remap), 512 threads. Waves 0-3 (grp A): even kv-tiles,
// waves 4-7 (grp B): odd. Wave pair (wq, wq+4) owns q-rows it*64+wq*16..+15.
// All threads cooperatively stage both tiles per iteration. LDS merge at end.
__global__ __launch_bounds__(512) void flash_attn_mfma(
    const u16* __restrict__ qkvb, u16* __restrict__ concatb)
{
    const int bid = blockIdx.x;
    const int lo = bid & 255;
    int it = lo >> 3;
    int h  = lo & 7;
    if (bid >= 256) { it = 31 - it; h += 8; }

    const u16* qh = qkvb + h * DHEAD;
    const u16* kh = qkvb + DMODEL + h * DHEAD;
    const u16* vh = qkvb + 2 * DMODEL + h * DHEAD;
    const int LDQ = 3 * DMODEL;

    __shared__ u16 Ks[2][64][72];    // [buf][kv][k], pad-72
    __shared__ u16 Vt[2][64][72];    // [buf][dv][kv], XOR-swizzled k-blocks

    const int tid = threadIdx.x;
    const int l = tid & 63, w = tid >> 6;
    const int grp = w >> 2, wq = w & 3;
    const int fr = l & 15, fg = l >> 4;

    // Q fragment: lane holds Q[q = wq*16+fr][k = fg*8..+7], 2 k-steps
    short8 qf[2];
    {
        const u16* qp = qh + (size_t)(it * 64 + wq * 16 + fr) * LDQ + fg * 8;
        qf[0] = *reinterpret_cast<const short8*>(qp);
        qf[1] = *reinterpret_cast<const short8*>(qp + 32);
    }

    // staging geometry over 512 threads: 128 kv rows per iteration
    const int kr  = tid >> 2;            // 0..127
    const int kb  = kr >> 6, krl = kr & 63;
    const int kc  = (tid & 3) * 16;
    const int vp  = tid >> 3;            // 0..63 row-pairs
    const int vb  = vp >> 5, vpl = vp & 31;
    const int vc  = (tid & 7) * 8;

    short8 kf0, kf1, vf0, vf1;
    auto PREFETCH = [&](int s) {
        const u16* kg = kh + (size_t)(s * 128 + kr) * LDQ + kc;
        kf0 = *reinterpret_cast<const short8*>(kg);
        kf1 = *reinterpret_cast<const short8*>(kg + 8);
        const u16* vg = vh + (size_t)(s * 128 + 2 * vp) * LDQ + vc;
        vf0 = *reinterpret_cast<const short8*>(vg);
        vf1 = *reinterpret_cast<const short8*>(vg + LDQ);
    };

    f32x4 o[4];
    #pragma unroll
    for (int n = 0; n < 4; ++n) o[n] = (f32x4){0.f, 0.f, 0.f, 0.f};
    float m_run = -INFINITY, l_run = 0.0f;    // lane-scalar: q = fr

    const int sA = fr + 16 * ((2 * fg) & 3);
    const int sB = sA + 16;
    const bool hi = (fg >= 2);

    const u16 (*KsG)[72] = Ks[grp];
    char* VtG = (char*)&Vt[grp][0][0];
    char* VtS = (char*)&Vt[vb][0][0];

    const int niter = (it >> 1) + 1;
    PREFETCH(0);

    for (int s = 0; s < niter; ++s) {
        __syncthreads();
        *reinterpret_cast<short8*>(&Ks[kb][krl][kc])     = kf0;
        *reinterpret_cast<short8*>(&Ks[kb][krl][kc + 8]) = kf1;
        #pragma unroll
        for (int i = 0; i < 8; ++i) {
            u32 word = (u32)(u16)vf0[i] | ((u32)(u16)vf1[i] << 16);
            int dv = vc + i;
            int off = 144 * dv + 16 * ((vpl >> 2) ^ ((dv >> 3) & 7)) + 4 * (vpl & 3);
            *reinterpret_cast<u32*>(VtS + off) = word;
        }
        if (s + 1 < niter) PREFETCH(s + 1);
        __syncthreads();

        const int jt = 2 * s + grp;
        if (jt > it) continue;               // group idle this iteration

        // S^T = K @ Q^T : s_[n] holds S[kv = n*16 + fg*4 + r][q = fr]
        f32x4 s_[4];
        #pragma unroll
        for (int n = 0; n < 4; ++n) s_[n] = (f32x4){0.f, 0.f, 0.f, 0.f};
        __builtin_amdgcn_s_setprio(1);
        #pragma unroll
        for (int n = 0; n < 4; ++n) {
            #pragma unroll
            for (int ks = 0; ks < 2; ++ks) {
                short8 kfrag = *reinterpret_cast<const short8*>(&KsG[n * 16 + fr][ks * 32 + fg * 8]);
                s_[n] = __builtin_amdgcn_mfma_f32_16x16x32_bf16(kfrag, qf[ks], s_[n], 0, 0, 0);
            }
        }
        __builtin_amdgcn_s_setprio(0);

        // in-register online softmax over this lane's q-row
        const bool diag = (jt == it);
        const int qrow_t = wq * 16 + fr;
        float sv[4][4];
        float pm = -INFINITY;
        #pragma unroll
        for (int n = 0; n < 4; ++n)
            #pragma unroll
            for (int r = 0; r < 4; ++r) {
                float v = s_[n][r] * 0.125f;
                if (diag && (n * 16 + fg * 4 + r) > qrow_t) v = -INFINITY;
                sv[n][r] = v;
                pm = fmaxf(pm, v);
            }
        pm = fmaxf(pm, __shfl_xor(pm, 16));
        pm = fmaxf(pm, __shfl_xor(pm, 32));
        float mnew = fmaxf(m_run, pm);
        float corr = __expf(m_run - mnew);
        float rs = 0.0f;
        float pp[4][4];
        #pragma unroll
        for (int n = 0; n < 4; ++n)
            #pragma unroll
            for (int r = 0; r < 4; ++r) {
                float pv = __expf(sv[n][r] - mnew);
                pp[n][r] = pv;
                rs += pv;
            }
        rs += __shfl_xor(rs, 16);
        rs += __shfl_xor(rs, 32);
        l_run = l_run * corr + rs;
        m_run = mnew;
        #pragma unroll
        for (int n = 0; n < 4; ++n) {
            o[n][0] *= corr; o[n][1] *= corr; o[n][2] *= corr; o[n][3] *= corr;
        }

        // pack P to bf16 pairs (truncation: P in [0,1], err <= 2^-8)
        u32 pk[4][2];
        #pragma unroll
        for (int n = 0; n < 4; ++n) {
            pk[n][0] = (__float_as_uint(pp[n][0]) >> 16) | (__float_as_uint(pp[n][1]) & 0xFFFF0000u);
            pk[n][1] = (__float_as_uint(pp[n][2]) >> 16) | (__float_as_uint(pp[n][3]) & 0xFFFF0000u);
        }

        // PV with in-register P redistribution
        __builtin_amdgcn_s_setprio(1);
        #pragma unroll
        for (int ks = 0; ks < 2; ++ks) {
            u32 a0 = __shfl(pk[2 * ks][0], sA);
            u32 a1 = __shfl(pk[2 * ks][1], sA);
            u32 a2 = __shfl(pk[2 * ks][0], sB);
            u32 a3 = __shfl(pk[2 * ks][1], sB);
            u32 b0 = __shfl(pk[2 * ks + 1][0], sA);
            u32 b1 = __shfl(pk[2 * ks + 1][1], sA);
            u32 b2 = __shfl(pk[2 * ks + 1][0], sB);
            u32 b3 = __shfl(pk[2 * ks + 1][1], sB);
            union { u32 u[4]; short8 s8; } pb;
            pb.u[0] = hi ? b0 : a0;
            pb.u[1] = hi ? b1 : a1;
            pb.u[2] = hi ? b2 : a2;
            pb.u[3] = hi ? b3 : a3;
            #pragma unroll
            for (int n = 0; n < 4; ++n) {
                int dv = n * 16 + fr;
                const short8* vfrag = reinterpret_cast<const short8*>(
                    VtG + 144 * dv + 16 * ((ks * 4 + fg) ^ ((dv >> 3) & 7)));
                o[n] = __builtin_amdgcn_mfma_f32_16x16x32_bf16(*vfrag, pb.s8, o[n], 0, 0, 0);
            }
        }
        __builtin_amdgcn_s_setprio(0);
    }

    // ---- merge group B partials into group A via LDS (overlay on Ks) ----
    __syncthreads();
    float* mrg = reinterpret_cast<float*>(&Ks[0][0][0]);
    const int slot = (wq * 64 + l) * 18;
    if (grp == 1) {
        #pragma unroll
        for (int n = 0; n < 4; ++n)
            #pragma unroll
            for (int r = 0; r < 4; ++r)
                mrg[slot + n * 4 + r] = o[n][r];
        mrg[slot + 16] = m_run;
        mrg[slot + 17] = l_run;
    }
    __syncthreads();
    if (grp == 0) {
        float mB = mrg[slot + 16], lB = mrg[slot + 17];
        float mstar = fmaxf(m_run, mB);
        float cA = __expf(m_run - mstar);
        float cB = __expf(mB - mstar);
        float inv = 1.0f / (l_run * cA + lB * cB);
        int qrow = it * 64 + wq * 16 + fr;
        #pragma unroll
        for (int n = 0; n < 4; ++n)
            #pragma unroll
            for (int r = 0; r < 4; ++r) {
                float val = (o[n][r] * cA + mrg[slot + n * 4 + r] * cB) * inv;
                concatb[(size_t)qrow * DMODEL + h * DHEAD + n * 16 + fg * 4 + r] = f2b(val);
            }
    }
}

// ---------------- fused partial-reduce + LayerNorm ----------------
template<int NPART, int RELUB, int DUAL>
__global__ __launch_bounds__(256) void ln_fuse(
    const float* __restrict__ P, size_t pstride,
    const float* __restrict__ base,
    const float* __restrict__ bias2,
    const float* __restrict__ g, const float* __restrict__ b,
    float* __restrict__ out, u16* __restrict__ outb)
{
    int row = blockIdx.x, tid = threadIdx.x;
    __shared__ float red[256];
    size_t off = (size_t)row * DMODEL + tid * 4;

    float4 acc = *reinterpret_cast<const float4*>(P + off);
    #pragma unroll
    for (int p = 1; p < NPART; ++p) {
        float4 t = *reinterpret_cast<const float4*>(P + (size_t)p * pstride + off);
        acc.x += t.x; acc.y += t.y; acc.z += t.z; acc.w += t.w;
    }
    if (RELUB) {
        float4 bb = *reinterpret_cast<const float4*>(bias2 + tid * 4);
        acc.x = fmaxf(acc.x + bb.x, 0.0f); acc.y = fmaxf(acc.y + bb.y, 0.0f);
        acc.z = fmaxf(acc.z + bb.z, 0.0f); acc.w = fmaxf(acc.w + bb.w, 0.0f);
    }
    float4 bs = *reinterpret_cast<const float4*>(base + off);
    float vals[4] = {acc.x + bs.x, acc.y + bs.y, acc.z + bs.z, acc.w + bs.w};

    float s = vals[0] + vals[1] + vals[2] + vals[3];
    red[tid] = s; __syncthreads();
    for (int st = 128; st > 0; st >>= 1) { if (tid < st) red[tid] += red[tid + st]; __syncthreads(); }
    float mu = red[0] * (1.0f / DMODEL);
    __syncthreads();

    float vs = 0.0f;
    #pragma unroll
    for (int i = 0; i < 4; ++i) { float d = vals[i] - mu; vs += d * d; }
    red[tid] = vs; __syncthreads();
    for (int st = 128; st > 0; st >>= 1) { if (tid < st) red[tid] += red[tid + st]; __syncthreads(); }
    float rstd = rsqrtf(red[0] * (1.0f / DMODEL) + LNEPS);

    float4 gv = *reinterpret_cast<const float4*>(g + tid * 4);
    float4 bv = *reinterpret_cast<const float4*>(b + tid * 4);
    float gs[4] = {gv.x, gv.y, gv.z, gv.w};
    float bsc[4] = {bv.x, bv.y, bv.z, bv.w};
    #pragma unroll
    for (int i = 0; i < 4; ++i) {
        float r = (vals[i] - mu) * rstd * gs[i] + bsc[i];
        out[off + i] = r;
        if (DUAL) outb[off + i] = f2b(r);
    }
}

// ---------------- launch ----------------
extern "C" void kernel_launch(void* const* d_in, const int* in_sizes, int n_in,
                              void* d_out, int out_size, void* d_ws, size_t ws_size,
                              hipStream_t stream)
{
    const float* x    = (const float*)d_in[0];
    const float* wq   = (const float*)d_in[1];
    const float* wk   = (const float*)d_in[2];
    const float* wv   = (const float*)d_in[3];
    const float* wo   = (const float*)d_in[4];
    const float* ln1g = (const float*)d_in[5];
    const float* ln1b = (const float*)d_in[6];
    const float* w1   = (const float*)d_in[7];
    const float* b1   = (const float*)d_in[8];
    const float* w2   = (const float*)d_in[9];
    const float* b2   = (const float*)d_in[10];
    const float* ln2g = (const float*)d_in[11];
    const float* ln2b = (const float*)d_in[12];
    float* out = (float*)d_out;

    char* ws = (char*)d_ws;
    const size_t MB = 1024 * 1024;
    u16*   w2T     = (u16*)  (ws + 0 * MB);
    float* h1      = (float*)(ws + 8 * MB);
    float* P01     = (float*)(ws + 16 * MB);  // 2 x 8 MB (oproj partials)
    u16*   ff1b    = (u16*)  (ws + 16 * MB);  // after LN1
    float* FP      = (float*)(ws + 32 * MB);  // 4 x 8 MB (ffn2 partials)
    u16*   wqkvT   = (u16*)  (ws + 32 * MB);
    u16*   woT     = (u16*)  (ws + 38 * MB);
    u16*   w1T     = (u16*)  (ws + 40 * MB);
    u16*   xb      = (u16*)  (ws + 48 * MB);
    u16*   concatb = (u16*)  (ws + 48 * MB);
    u16*   h1b     = (u16*)  (ws + 48 * MB);
    u16*   qkvb    = (u16*)  (ws + 52 * MB);

    const size_t PSTRIDE = (size_t)NTOK * DMODEL;

    dim3 blk(256);

    cast_f32_bf16<<<dim3(NTOK * DMODEL / 1024), blk, 0, stream>>>(x, xb, NTOK * DMODEL);
    cast_wqkv<<<dim3(2, 32, 48), blk, 0, stream>>>(wq, wk, wv, wqkvT);
    transpose_cast<<<dim3(32, 32),  blk, 0, stream>>>(wo, DMODEL, woT, DMODEL);
    transpose_cast<<<dim3(128, 32), blk, 0, stream>>>(w1, DFF, w1T, DMODEL);
    transpose_cast<<<dim3(32, 128), blk, 0, stream>>>(w2, DMODEL, w2T, DFF);

    mfma_gemm<0,0,0,1,1><<<dim3(24, 16), blk, 0, stream>>>(
        xb, DMODEL, wqkvT, DMODEL, qkvb, 3 * DMODEL, DMODEL, nullptr, nullptr, 0, 0);
    flash_attn_mfma<<<dim3(512), dim3(512), 0, stream>>>(qkvb, concatb);
    mfma_gemm<0,0,0,0,2><<<dim3(8, 16, 2), blk, 0, stream>>>(
        concatb, DMODEL, woT, DMODEL, P01, DMODEL, 512, nullptr, nullptr, 0, PSTRIDE);
    ln_fuse<2,0,1><<<dim3(NTOK), blk, 0, stream>>>(
        P01, PSTRIDE, x, nullptr, ln1g, ln1b, h1, h1b);
    mfma_gemm<1,1,0,1,1><<<dim3(32, 16), blk, 0, stream>>>(
        h1b, DMODEL, w1T, DMODEL, ff1b, DFF, DMODEL, b1, nullptr, 0, 0);
    mfma_gemm<0,0,0,0,4><<<dim3(8, 16, 4), blk, 0, stream>>>(
        ff1b, DFF, w2T, DFF, FP, DMODEL, 1024, nullptr, nullptr, 0, PSTRIDE);
    ln_fuse<4,1,0><<<dim3(NTOK), blk, 0, stream>>>(
        FP, PSTRIDE, h1, b2, ln2g, ln2b, out, nullptr);
}

// Round 10
// 166.620 us; speedup vs baseline: 1.2505x; 1.0491x over previous
//
#include <hip/hip_runtime.h>
#include <math.h>

// TransformerBlock N=2048, D=1024, H=16, DK=DV=64, FF=4096.
// Round 10: (1) all prep casts/transposes fused into one kernel;
// (2) flash stages 4 kv-tiles/iteration (2 per group) -> half the barriers;
// (3) defer-max (T13) skips o/l rescale when max growth <= 8.
// GEMMs / LN unchanged.

#define NTOK   2048
#define DMODEL 1024
#define NHEAD  16
#define DHEAD  64
#define DFF    4096
#define LNEPS  1e-5f

typedef unsigned int   u32;
typedef unsigned short u16;
typedef __attribute__((ext_vector_type(8))) short short8;
typedef __attribute__((ext_vector_type(4))) float f32x4;

__device__ __forceinline__ u16 f2b(float f) {
    u32 b = __float_as_uint(f);
    b += 0x7FFFu + ((b >> 16) & 1u);   // RNE
    return (u16)(b >> 16);
}

#define AS1(p) ((const __attribute__((address_space(1))) u32*)(p))
#define AS3(p) ((__attribute__((address_space(3))) u32*)(p))

// ---------------- bf16 MFMA GEMM, 128x128 tile, BK=32, 2-phase dbuf --------
template<int RELU, int BIAS, int RESID, int OUT_BF16, int SPLITK>
__global__ __launch_bounds__(256) void mfma_gemm(
    const u16* __restrict__ A, int lda,
    const u16* __restrict__ Bt, int ldbt,
    void* __restrict__ Cp, int ldc, int Kc,
    const float* __restrict__ bias,
    const float* __restrict__ resid, int ldr,
    size_t pstride)
{
    __shared__ u16 As[2][128 * 32];
    __shared__ u16 Bs[2][128 * 32];

    const int tid = threadIdx.x;
    const int l = tid & 63, w = tid >> 6;
    const int row0 = blockIdx.y * 128, col0 = blockIdx.x * 128;
    const int kbase = (SPLITK > 1) ? blockIdx.z * Kc : 0;

    f32x4 acc[4][4];
    #pragma unroll
    for (int m = 0; m < 4; ++m)
        #pragma unroll
        for (int n = 0; n < 4; ++n)
            acc[m][n] = (f32x4){0.f, 0.f, 0.f, 0.f};

    const int srow = w * 32 + (l >> 2);
    const int skk  = (l & 3) * 8;
    const u16* Ag = A  + (size_t)(row0 + srow) * lda  + kbase + skk;
    const u16* Bg = Bt + (size_t)(col0 + srow) * ldbt + kbase + skk;

    const int fr  = l & 15;
    const int fk  = (l >> 4) * 8;
    const int ar0 = (w >> 1) * 64;
    const int bc0 = (w & 1) * 64;

    auto STAGE = [&](int buf, int k0) {
        char* AsB = (char*)&As[buf][0] + w * 2048;
        char* BsB = (char*)&Bs[buf][0] + w * 2048;
        __builtin_amdgcn_global_load_lds(AS1(Ag + k0),                     AS3(AsB),        16, 0, 0);
        __builtin_amdgcn_global_load_lds(AS1(Ag + k0 + (size_t)16 * lda),  AS3(AsB + 1024), 16, 0, 0);
        __builtin_amdgcn_global_load_lds(AS1(Bg + k0),                     AS3(BsB),        16, 0, 0);
        __builtin_amdgcn_global_load_lds(AS1(Bg + k0 + (size_t)16 * ldbt), AS3(BsB + 1024), 16, 0, 0);
    };

    STAGE(0, 0);
    int cur = 0;
    for (int k0 = 0; k0 < Kc; k0 += 32) {
        __syncthreads();
        if (k0 + 32 < Kc) STAGE(cur ^ 1, k0 + 32);

        short8 af[4], bfr[4];
        #pragma unroll
        for (int m = 0; m < 4; ++m)
            af[m] = *reinterpret_cast<const short8*>(&As[cur][(ar0 + m * 16 + fr) * 32 + fk]);
        #pragma unroll
        for (int n = 0; n < 4; ++n)
            bfr[n] = *reinterpret_cast<const short8*>(&Bs[cur][(bc0 + n * 16 + fr) * 32 + fk]);
        #pragma unroll
        for (int m = 0; m < 4; ++m)
            #pragma unroll
            for (int n = 0; n < 4; ++n)
                acc[m][n] = __builtin_amdgcn_mfma_f32_16x16x32_bf16(af[m], bfr[n], acc[m][n], 0, 0, 0);
        cur ^= 1;
    }

    if (SPLITK > 1) {
        float* Pp = (float*)Cp + blockIdx.z * pstride;
        #pragma unroll
        for (int m = 0; m < 4; ++m)
            #pragma unroll
            for (int n = 0; n < 4; ++n)
                #pragma unroll
                for (int r = 0; r < 4; ++r) {
                    int row = row0 + ar0 + m * 16 + (l >> 4) * 4 + r;
                    int col = col0 + bc0 + n * 16 + (l & 15);
                    Pp[(size_t)row * ldc + col] = acc[m][n][r];
                }
        return;
    }

    #pragma unroll
    for (int m = 0; m < 4; ++m) {
        #pragma unroll
        for (int n = 0; n < 4; ++n) {
            #pragma unroll
            for (int r = 0; r < 4; ++r) {
                int row = row0 + ar0 + m * 16 + (l >> 4) * 4 + r;
                int col = col0 + bc0 + n * 16 + (l & 15);
                float val = acc[m][n][r];
                if (BIAS)  val += bias[col];
                if (RESID) val += resid[(size_t)row * ldr + col];
                if (RELU)  val = fmaxf(val, 0.0f);
                if (OUT_BF16) ((u16*)Cp)[(size_t)row * ldc + col] = f2b(val);
                else          ((float*)Cp)[(size_t)row * ldc + col] = val;
            }
        }
    }
}

// ---------------- fused prep: x cast + all weight transposes ----------------
__device__ __forceinline__ void transpose_tile32(
    const float* __restrict__ in, int ldin,
    u16* __restrict__ out, int ldout, int r0, int c0)
{
    __shared__ float tile[32][33];
    int tx = threadIdx.x & 31, ty = threadIdx.x >> 5;
    #pragma unroll
    for (int i = 0; i < 4; ++i) {
        int r = ty + i * 8;
        tile[r][tx] = in[(size_t)(r0 + r) * ldin + c0 + tx];
    }
    __syncthreads();
    #pragma unroll
    for (int i = 0; i < 4; ++i) {
        int rr = ty + i * 8;
        out[(size_t)(c0 + rr) * ldout + r0 + tx] = f2b(tile[tx][rr]);
    }
}

// grid 13312: [0,1024) x cast (8 elems/thread); [1024,4096) wqkv;
// [4096,5120) wo; [5120,9216) w1; [9216,13312) w2.
__global__ __launch_bounds__(256) void prep_all(
    const float* __restrict__ x,
    const float* __restrict__ wq, const float* __restrict__ wk, const float* __restrict__ wv,
    const float* __restrict__ wo, const float* __restrict__ w1, const float* __restrict__ w2,
    u16* __restrict__ xb, u16* __restrict__ wqkvT, u16* __restrict__ woT,
    u16* __restrict__ w1T, u16* __restrict__ w2T)
{
    int b = blockIdx.x;
    if (b < 1024) {
        int i = (b * 256 + threadIdx.x) * 8;
        float4 v0 = *reinterpret_cast<const float4*>(x + i);
        float4 v1 = *reinterpret_cast<const float4*>(x + i + 4);
        ushort4 o0, o1;
        o0.x = f2b(v0.x); o0.y = f2b(v0.y); o0.z = f2b(v0.z); o0.w = f2b(v0.w);
        o1.x = f2b(v1.x); o1.y = f2b(v1.y); o1.z = f2b(v1.z); o1.w = f2b(v1.w);
        *reinterpret_cast<ushort4*>(xb + i)     = o0;
        *reinterpret_cast<ushort4*>(xb + i + 4) = o1;
    } else if (b < 4096) {
        int u = b - 1024;
        int z = u >> 6, t = u & 63;
        int p = z >> 4, hh = z & 15;
        const float* in = (p == 0 ? wq : p == 1 ? wk : wv) + (size_t)hh * DMODEL * DHEAD;
        u16* out = wqkvT + (size_t)(p * 1024 + hh * 64) * DMODEL;
        transpose_tile32(in, DHEAD, out, DMODEL, (t >> 1) * 32, (t & 1) * 32);
    } else if (b < 5120) {
        int u = b - 4096;
        transpose_tile32(wo, DMODEL, woT, DMODEL, (u >> 5) * 32, (u & 31) * 32);
    } else if (b < 9216) {
        int u = b - 5120;
        transpose_tile32(w1, DFF, w1T, DMODEL, (u >> 7) * 32, (u & 127) * 32);
    } else {
        int u = b - 9216;
        transpose_tile32(w2, DMODEL, w2T, DFF, (u >> 5) * 32, (u & 31) * 32);
    }
}

// ---------------- 8-wave split-KV swapped-operand flash attention ----------
// 512 blocks (pair remap), 512 threads. grp = w>>2 in {0,1}; iteration s
// stages 4 kv-tiles (256 rows); grp g computes tiles 4s+2g and 4s+2g+1.
// LDS merge of group partials at the end. Defer-max (THR=8) on rescale.
__global__ __launch_bounds__(512) void flash_attn_mfma(
    const u16* __restrict__ qkvb, u16* __restrict__ concatb)
{
    const int bid = blockIdx.x;
    const int lo = bid & 255;
    int it = lo >> 3;
    int h  = lo & 7;
    if (bid >= 256) { it = 31 - it; h += 8; }

    const u16* qh = qkvb + h * DHEAD;
    const u16* kh = qkvb + DMODEL + h * DHEAD;
    const u16* vh = qkvb + 2 * DMODEL + h * DHEAD;
    const int LDQ = 3 * DMODEL;

    __shared__ u16 Ks[4][64][72];    // [tile][kv][k], pad-72
    __shared__ u16 Vt[4][64][72];    // [tile][dv][kv], XOR-swizzled chunks

    const int tid = threadIdx.x;
    const int l = tid & 63, w = tid >> 6;
    const int grp = w >> 2, wq = w & 3;
    const int fr = l & 15, fg = l >> 4;

    // Q fragment: lane holds Q[q = wq*16+fr][k = fg*8..+7], 2 k-steps
    short8 qf[2];
    {
        const u16* qp = qh + (size_t)(it * 64 + wq * 16 + fr) * LDQ + fg * 8;
        qf[0] = *reinterpret_cast<const short8*>(qp);
        qf[1] = *reinterpret_cast<const short8*>(qp + 32);
    }

    // staging over 512 threads: 256 kv rows per iteration
    const int kr  = tid >> 1;            // 0..255
    const int kb  = kr >> 6, krl = kr & 63;
    const int kc  = (tid & 1) * 32;
    const int vp  = tid >> 2;            // 0..127 row-pairs
    const int vb  = vp >> 5, vpl = vp & 31;
    const int vc  = (tid & 3) * 16;

    short8 kf[4], vf0[2], vf1[2];
    auto PREFETCH = [&](int s) {
        const u16* kg = kh + (size_t)(s * 256 + kr) * LDQ + kc;
        kf[0] = *reinterpret_cast<const short8*>(kg);
        kf[1] = *reinterpret_cast<const short8*>(kg + 8);
        kf[2] = *reinterpret_cast<const short8*>(kg + 16);
        kf[3] = *reinterpret_cast<const short8*>(kg + 24);
        const u16* vg = vh + (size_t)(s * 256 + 2 * vp) * LDQ + vc;
        vf0[0] = *reinterpret_cast<const short8*>(vg);
        vf0[1] = *reinterpret_cast<const short8*>(vg + 8);
        vf1[0] = *reinterpret_cast<const short8*>(vg + LDQ);
        vf1[1] = *reinterpret_cast<const short8*>(vg + LDQ + 8);
    };

    f32x4 o[4];
    #pragma unroll
    for (int n = 0; n < 4; ++n) o[n] = (f32x4){0.f, 0.f, 0.f, 0.f};
    float m_run = -INFINITY, l_run = 0.0f;    // lane-scalar: q = fr

    const int sA = fr + 16 * ((2 * fg) & 3);
    const int sB = sA + 16;
    const bool hi = (fg >= 2);

    char* VtSb = (char*)&Vt[vb][0][0];

    const int niter = (it >> 2) + 1;
    PREFETCH(0);

    for (int s = 0; s < niter; ++s) {
        __syncthreads();
        *reinterpret_cast<short8*>(&Ks[kb][krl][kc +  0]) = kf[0];
        *reinterpret_cast<short8*>(&Ks[kb][krl][kc +  8]) = kf[1];
        *reinterpret_cast<short8*>(&Ks[kb][krl][kc + 16]) = kf[2];
        *reinterpret_cast<short8*>(&Ks[kb][krl][kc + 24]) = kf[3];
        #pragma unroll
        for (int c2 = 0; c2 < 2; ++c2) {
            #pragma unroll
            for (int i = 0; i < 8; ++i) {
                u32 word = (u32)(u16)vf0[c2][i] | ((u32)(u16)vf1[c2][i] << 16);
                int dv = vc + c2 * 8 + i;
                int off = 144 * dv + 16 * ((vpl >> 2) ^ ((dv >> 3) & 7)) + 4 * (vpl & 3);
                *reinterpret_cast<u32*>(VtSb + off) = word;
            }
        }
        if (s + 1 < niter) PREFETCH(s + 1);
        __syncthreads();

        #pragma unroll
        for (int t = 0; t < 2; ++t) {
            const int jt = 4 * s + 2 * grp + t;
            if (jt > it) continue;
            const int buf = 2 * grp + t;
            const u16 (*KsG)[72] = Ks[buf];
            char* VtG = (char*)&Vt[buf][0][0];

            // S^T = K @ Q^T : s_[n] holds S[kv = n*16 + fg*4 + r][q = fr]
            f32x4 s_[4];
            #pragma unroll
            for (int n = 0; n < 4; ++n) s_[n] = (f32x4){0.f, 0.f, 0.f, 0.f};
            __builtin_amdgcn_s_setprio(1);
            #pragma unroll
            for (int n = 0; n < 4; ++n) {
                #pragma unroll
                for (int ks = 0; ks < 2; ++ks) {
                    short8 kfrag = *reinterpret_cast<const short8*>(&KsG[n * 16 + fr][ks * 32 + fg * 8]);
                    s_[n] = __builtin_amdgcn_mfma_f32_16x16x32_bf16(kfrag, qf[ks], s_[n], 0, 0, 0);
                }
            }
            __builtin_amdgcn_s_setprio(0);

            // in-register online softmax (lane owns q-row fr)
            const bool diag = (jt == it);
            const int qrow_t = wq * 16 + fr;
            float sv[4][4];
            float pm = -INFINITY;
            #pragma unroll
            for (int n = 0; n < 4; ++n)
                #pragma unroll
                for (int r = 0; r < 4; ++r) {
                    float v = s_[n][r] * 0.125f;
                    if (diag && (n * 16 + fg * 4 + r) > qrow_t) v = -INFINITY;
                    sv[n][r] = v;
                    pm = fmaxf(pm, v);
                }
            pm = fmaxf(pm, __shfl_xor(pm, 16));
            pm = fmaxf(pm, __shfl_xor(pm, 32));
            // defer-max (T13): only rescale when max grew past threshold
            if (!__all(pm <= m_run + 8.0f)) {
                float mnew = fmaxf(m_run, pm);
                float corr = __expf(m_run - mnew);
                l_run *= corr;
                #pragma unroll
                for (int n = 0; n < 4; ++n) {
                    o[n][0] *= corr; o[n][1] *= corr; o[n][2] *= corr; o[n][3] *= corr;
                }
                m_run = mnew;
            }
            float rs = 0.0f;
            float pp[4][4];
            #pragma unroll
            for (int n = 0; n < 4; ++n)
                #pragma unroll
                for (int r = 0; r < 4; ++r) {
                    float pv = __expf(sv[n][r] - m_run);
                    pp[n][r] = pv;
                    rs += pv;
                }
            rs += __shfl_xor(rs, 16);
            rs += __shfl_xor(rs, 32);
            l_run += rs;

            // pack P to bf16 pairs (truncation: P bounded, err <= 2^-8 rel)
            u32 pk[4][2];
            #pragma unroll
            for (int n = 0; n < 4; ++n) {
                pk[n][0] = (__float_as_uint(pp[n][0]) >> 16) | (__float_as_uint(pp[n][1]) & 0xFFFF0000u);
                pk[n][1] = (__float_as_uint(pp[n][2]) >> 16) | (__float_as_uint(pp[n][3]) & 0xFFFF0000u);
            }

            // PV with in-register P redistribution
            __builtin_amdgcn_s_setprio(1);
            #pragma unroll
            for (int ks = 0; ks < 2; ++ks) {
                u32 a0 = __shfl(pk[2 * ks][0], sA);
                u32 a1 = __shfl(pk[2 * ks][1], sA);
                u32 a2 = __shfl(pk[2 * ks][0], sB);
                u32 a3 = __shfl(pk[2 * ks][1], sB);
                u32 b0 = __shfl(pk[2 * ks + 1][0], sA);
                u32 b1 = __shfl(pk[2 * ks + 1][1], sA);
                u32 b2 = __shfl(pk[2 * ks + 1][0], sB);
                u32 b3 = __shfl(pk[2 * ks + 1][1], sB);
                union { u32 u[4]; short8 s8; } pb;
                pb.u[0] = hi ? b0 : a0;
                pb.u[1] = hi ? b1 : a1;
                pb.u[2] = hi ? b2 : a2;
                pb.u[3] = hi ? b3 : a3;
                #pragma unroll
                for (int n = 0; n < 4; ++n) {
                    int dv = n * 16 + fr;
                    const short8* vfrag = reinterpret_cast<const short8*>(
                        VtG + 144 * dv + 16 * ((ks * 4 + fg) ^ ((dv >> 3) & 7)));
                    o[n] = __builtin_amdgcn_mfma_f32_16x16x32_bf16(*vfrag, pb.s8, o[n], 0, 0, 0);
                }
            }
            __builtin_amdgcn_s_setprio(0);
        }
    }

    // ---- merge group B partials into group A via LDS (overlay on Ks) ----
    __syncthreads();
    float* mrg = reinterpret_cast<float*>(&Ks[0][0][0]);
    const int slot = (wq * 64 + l) * 18;
    if (grp == 1) {
        #pragma unroll
        for (int n = 0; n < 4; ++n)
            #pragma unroll
            for (int r = 0; r < 4; ++r)
                mrg[slot + n * 4 + r] = o[n][r];
        mrg[slot + 16] = m_run;
        mrg[slot + 17] = l_run;
    }
    __syncthreads();
    if (grp == 0) {
        float mB = mrg[slot + 16], lB = mrg[slot + 17];
        float mstar = fmaxf(m_run, mB);
        float cA = __expf(m_run - mstar);
        float cB = __expf(mB - mstar);
        float inv = 1.0f / (l_run * cA + lB * cB);
        int qrow = it * 64 + wq * 16 + fr;
        #pragma unroll
        for (int n = 0; n < 4; ++n)
            #pragma unroll
            for (int r = 0; r < 4; ++r) {
                float val = (o[n][r] * cA + mrg[slot + n * 4 + r] * cB) * inv;
                concatb[(size_t)qrow * DMODEL + h * DHEAD + n * 16 + fg * 4 + r] = f2b(val);
            }
    }
}

// ---------------- fused partial-reduce + LayerNorm ----------------
template<int NPART, int RELUB, int DUAL>
__global__ __launch_bounds__(256) void ln_fuse(
    const float* __restrict__ P, size_t pstride,
    const float* __restrict__ base,
    const float* __restrict__ bias2,
    const float* __restrict__ g, const float* __restrict__ b,
    float* __restrict__ out, u16* __restrict__ outb)
{
    int row = blockIdx.x, tid = threadIdx.x;
    __shared__ float red[256];
    size_t off = (size_t)row * DMODEL + tid * 4;

    float4 acc = *reinterpret_cast<const float4*>(P + off);
    #pragma unroll
    for (int p = 1; p < NPART; ++p) {
        float4 t = *reinterpret_cast<const float4*>(P + (size_t)p * pstride + off);
        acc.x += t.x; acc.y += t.y; acc.z += t.z; acc.w += t.w;
    }
    if (RELUB) {
        float4 bb = *reinterpret_cast<const float4*>(bias2 + tid * 4);
        acc.x = fmaxf(acc.x + bb.x, 0.0f); acc.y = fmaxf(acc.y + bb.y, 0.0f);
        acc.z = fmaxf(acc.z + bb.z, 0.0f); acc.w = fmaxf(acc.w + bb.w, 0.0f);
    }
    float4 bs = *reinterpret_cast<const float4*>(base + off);
    float vals[4] = {acc.x + bs.x, acc.y + bs.y, acc.z + bs.z, acc.w + bs.w};

    float s = vals[0] + vals[1] + vals[2] + vals[3];
    red[tid] = s; __syncthreads();
    for (int st = 128; st > 0; st >>= 1) { if (tid < st) red[tid] += red[tid + st]; __syncthreads(); }
    float mu = red[0] * (1.0f / DMODEL);
    __syncthreads();

    float vs = 0.0f;
    #pragma unroll
    for (int i = 0; i < 4; ++i) { float d = vals[i] - mu; vs += d * d; }
    red[tid] = vs; __syncthreads();
    for (int st = 128; st > 0; st >>= 1) { if (tid < st) red[tid] += red[tid + st]; __syncthreads(); }
    float rstd = rsqrtf(red[0] * (1.0f / DMODEL) + LNEPS);

    float4 gv = *reinterpret_cast<const float4*>(g + tid * 4);
    float4 bv = *reinterpret_cast<const float4*>(b + tid * 4);
    float gs[4] = {gv.x, gv.y, gv.z, gv.w};
    float bsc[4] = {bv.x, bv.y, bv.z, bv.w};
    #pragma unroll
    for (int i = 0; i < 4; ++i) {
        float r = (vals[i] - mu) * rstd * gs[i] + bsc[i];
        out[off + i] = r;
        if (DUAL) outb[off + i] = f2b(r);
    }
}

// ---------------- launch ----------------
extern "C" void kernel_launch(void* const* d_in, const int* in_sizes, int n_in,
                              void* d_out, int out_size, void* d_ws, size_t ws_size,
                              hipStream_t stream)
{
    const float* x    = (const float*)d_in[0];
    const float* wq   = (const float*)d_in[1];
    const float* wk   = (const float*)d_in[2];
    const float* wv   = (const float*)d_in[3];
    const float* wo   = (const float*)d_in[4];
    const float* ln1g = (const float*)d_in[5];
    const float* ln1b = (const float*)d_in[6];
    const float* w1   = (const float*)d_in[7];
    const float* b1   = (const float*)d_in[8];
    const float* w2   = (const float*)d_in[9];
    const float* b2   = (const float*)d_in[10];
    const float* ln2g = (const float*)d_in[11];
    const float* ln2b = (const float*)d_in[12];
    float* out = (float*)d_out;

    char* ws = (char*)d_ws;
    const size_t MB = 1024 * 1024;
    u16*   w2T     = (u16*)  (ws + 0 * MB);
    float* h1      = (float*)(ws + 8 * MB);
    float* P01     = (float*)(ws + 16 * MB);  // 2 x 8 MB (oproj partials)
    u16*   ff1b    = (u16*)  (ws + 16 * MB);  // after LN1
    float* FP      = (float*)(ws + 32 * MB);  // 4 x 8 MB (ffn2 partials)
    u16*   wqkvT   = (u16*)  (ws + 32 * MB);
    u16*   woT     = (u16*)  (ws + 38 * MB);
    u16*   w1T     = (u16*)  (ws + 40 * MB);
    u16*   xb      = (u16*)  (ws + 48 * MB);
    u16*   concatb = (u16*)  (ws + 48 * MB);
    u16*   h1b     = (u16*)  (ws + 48 * MB);
    u16*   qkvb    = (u16*)  (ws + 52 * MB);

    const size_t PSTRIDE = (size_t)NTOK * DMODEL;

    dim3 blk(256);

    prep_all<<<dim3(13312), blk, 0, stream>>>(x, wq, wk, wv, wo, w1, w2,
                                              xb, wqkvT, woT, w1T, w2T);

    mfma_gemm<0,0,0,1,1><<<dim3(24, 16), blk, 0, stream>>>(
        xb, DMODEL, wqkvT, DMODEL, qkvb, 3 * DMODEL, DMODEL, nullptr, nullptr, 0, 0);
    flash_attn_mfma<<<dim3(512), dim3(512), 0, stream>>>(qkvb, concatb);
    mfma_gemm<0,0,0,0,2><<<dim3(8, 16, 2), blk, 0, stream>>>(
        concatb, DMODEL, woT, DMODEL, P01, DMODEL, 512, nullptr, nullptr, 0, PSTRIDE);
    ln_fuse<2,0,1><<<dim3(NTOK), blk, 0, stream>>>(
        P01, PSTRIDE, x, nullptr, ln1g, ln1b, h1, h1b);
    mfma_gemm<1,1,0,1,1><<<dim3(32, 16), blk, 0, stream>>>(
        h1b, DMODEL, w1T, DMODEL, ff1b, DFF, DMODEL, b1, nullptr, 0, 0);
    mfma_gemm<0,0,0,0,4><<<dim3(8, 16, 4), blk, 0, stream>>>(
        ff1b, DFF, w2T, DFF, FP, DMODEL, 1024, nullptr, nullptr, 0, PSTRIDE);
    ln_fuse<4,1,0><<<dim3(NTOK), blk, 0, stream>>>(
        FP, PSTRIDE, h1, b2, ln2g, ln2b, out, nullptr);
}

// Round 11
// 160.313 us; speedup vs baseline: 1.2997x; 1.0393x over previous
//
#include <hip/hip_runtime.h>
#include <math.h>

// TransformerBlock N=2048, D=1024, H=16, DK=DV=64, FF=4096.
// Round 11: fp16 split-K partials (oproj now split-4 too) — quarters the
// ffn2 partial HBM traffic (64MB->16MB each way); LN2 residual base reads
// bf16 h1b (fp32 h1 copy removed). Flash/GEMM core unchanged.

#define NTOK   2048
#define DMODEL 1024
#define NHEAD  16
#define DHEAD  64
#define DFF    4096
#define LNEPS  1e-5f

typedef unsigned int   u32;
typedef unsigned short u16;
typedef _Float16       f16;
typedef __attribute__((ext_vector_type(8))) short short8;
typedef __attribute__((ext_vector_type(4))) float f32x4;
typedef __attribute__((ext_vector_type(4))) _Float16 f16x4;

__device__ __forceinline__ u16 f2b(float f) {
    u32 b = __float_as_uint(f);
    b += 0x7FFFu + ((b >> 16) & 1u);   // RNE
    return (u16)(b >> 16);
}
__device__ __forceinline__ float b2f(u16 v) {
    return __uint_as_float((u32)v << 16);
}

#define AS1(p) ((const __attribute__((address_space(1))) u32*)(p))
#define AS3(p) ((__attribute__((address_space(3))) u32*)(p))

// ---------------- bf16 MFMA GEMM, 128x128 tile, BK=32, 2-phase dbuf --------
// SPLITK>1: fp16 partials to (f16*)Cp + z*pstride. Else fused epilogue.
template<int RELU, int BIAS, int RESID, int OUT_BF16, int SPLITK>
__global__ __launch_bounds__(256) void mfma_gemm(
    const u16* __restrict__ A, int lda,
    const u16* __restrict__ Bt, int ldbt,
    void* __restrict__ Cp, int ldc, int Kc,
    const float* __restrict__ bias,
    const float* __restrict__ resid, int ldr,
    size_t pstride)
{
    __shared__ u16 As[2][128 * 32];
    __shared__ u16 Bs[2][128 * 32];

    const int tid = threadIdx.x;
    const int l = tid & 63, w = tid >> 6;
    const int row0 = blockIdx.y * 128, col0 = blockIdx.x * 128;
    const int kbase = (SPLITK > 1) ? blockIdx.z * Kc : 0;

    f32x4 acc[4][4];
    #pragma unroll
    for (int m = 0; m < 4; ++m)
        #pragma unroll
        for (int n = 0; n < 4; ++n)
            acc[m][n] = (f32x4){0.f, 0.f, 0.f, 0.f};

    const int srow = w * 32 + (l >> 2);
    const int skk  = (l & 3) * 8;
    const u16* Ag = A  + (size_t)(row0 + srow) * lda  + kbase + skk;
    const u16* Bg = Bt + (size_t)(col0 + srow) * ldbt + kbase + skk;

    const int fr  = l & 15;
    const int fk  = (l >> 4) * 8;
    const int ar0 = (w >> 1) * 64;
    const int bc0 = (w & 1) * 64;

    auto STAGE = [&](int buf, int k0) {
        char* AsB = (char*)&As[buf][0] + w * 2048;
        char* BsB = (char*)&Bs[buf][0] + w * 2048;
        __builtin_amdgcn_global_load_lds(AS1(Ag + k0),                     AS3(AsB),        16, 0, 0);
        __builtin_amdgcn_global_load_lds(AS1(Ag + k0 + (size_t)16 * lda),  AS3(AsB + 1024), 16, 0, 0);
        __builtin_amdgcn_global_load_lds(AS1(Bg + k0),                     AS3(BsB),        16, 0, 0);
        __builtin_amdgcn_global_load_lds(AS1(Bg + k0 + (size_t)16 * ldbt), AS3(BsB + 1024), 16, 0, 0);
    };

    STAGE(0, 0);
    int cur = 0;
    for (int k0 = 0; k0 < Kc; k0 += 32) {
        __syncthreads();
        if (k0 + 32 < Kc) STAGE(cur ^ 1, k0 + 32);

        short8 af[4], bfr[4];
        #pragma unroll
        for (int m = 0; m < 4; ++m)
            af[m] = *reinterpret_cast<const short8*>(&As[cur][(ar0 + m * 16 + fr) * 32 + fk]);
        #pragma unroll
        for (int n = 0; n < 4; ++n)
            bfr[n] = *reinterpret_cast<const short8*>(&Bs[cur][(bc0 + n * 16 + fr) * 32 + fk]);
        #pragma unroll
        for (int m = 0; m < 4; ++m)
            #pragma unroll
            for (int n = 0; n < 4; ++n)
                acc[m][n] = __builtin_amdgcn_mfma_f32_16x16x32_bf16(af[m], bfr[n], acc[m][n], 0, 0, 0);
        cur ^= 1;
    }

    if (SPLITK > 1) {
        f16* Pp = (f16*)Cp + blockIdx.z * pstride;
        #pragma unroll
        for (int m = 0; m < 4; ++m)
            #pragma unroll
            for (int n = 0; n < 4; ++n)
                #pragma unroll
                for (int r = 0; r < 4; ++r) {
                    int row = row0 + ar0 + m * 16 + (l >> 4) * 4 + r;
                    int col = col0 + bc0 + n * 16 + (l & 15);
                    Pp[(size_t)row * ldc + col] = (f16)acc[m][n][r];
                }
        return;
    }

    #pragma unroll
    for (int m = 0; m < 4; ++m) {
        #pragma unroll
        for (int n = 0; n < 4; ++n) {
            #pragma unroll
            for (int r = 0; r < 4; ++r) {
                int row = row0 + ar0 + m * 16 + (l >> 4) * 4 + r;
                int col = col0 + bc0 + n * 16 + (l & 15);
                float val = acc[m][n][r];
                if (BIAS)  val += bias[col];
                if (RESID) val += resid[(size_t)row * ldr + col];
                if (RELU)  val = fmaxf(val, 0.0f);
                if (OUT_BF16) ((u16*)Cp)[(size_t)row * ldc + col] = f2b(val);
                else          ((float*)Cp)[(size_t)row * ldc + col] = val;
            }
        }
    }
}

// ---------------- fused prep: x cast + all weight transposes ----------------
__device__ __forceinline__ void transpose_tile32(
    const float* __restrict__ in, int ldin,
    u16* __restrict__ out, int ldout, int r0, int c0)
{
    __shared__ float tile[32][33];
    int tx = threadIdx.x & 31, ty = threadIdx.x >> 5;
    #pragma unroll
    for (int i = 0; i < 4; ++i) {
        int r = ty + i * 8;
        tile[r][tx] = in[(size_t)(r0 + r) * ldin + c0 + tx];
    }
    __syncthreads();
    #pragma unroll
    for (int i = 0; i < 4; ++i) {
        int rr = ty + i * 8;
        out[(size_t)(c0 + rr) * ldout + r0 + tx] = f2b(tile[tx][rr]);
    }
}

__global__ __launch_bounds__(256) void prep_all(
    const float* __restrict__ x,
    const float* __restrict__ wq, const float* __restrict__ wk, const float* __restrict__ wv,
    const float* __restrict__ wo, const float* __restrict__ w1, const float* __restrict__ w2,
    u16* __restrict__ xb, u16* __restrict__ wqkvT, u16* __restrict__ woT,
    u16* __restrict__ w1T, u16* __restrict__ w2T)
{
    int b = blockIdx.x;
    if (b < 1024) {
        int i = (b * 256 + threadIdx.x) * 8;
        float4 v0 = *reinterpret_cast<const float4*>(x + i);
        float4 v1 = *reinterpret_cast<const float4*>(x + i + 4);
        ushort4 o0, o1;
        o0.x = f2b(v0.x); o0.y = f2b(v0.y); o0.z = f2b(v0.z); o0.w = f2b(v0.w);
        o1.x = f2b(v1.x); o1.y = f2b(v1.y); o1.z = f2b(v1.z); o1.w = f2b(v1.w);
        *reinterpret_cast<ushort4*>(xb + i)     = o0;
        *reinterpret_cast<ushort4*>(xb + i + 4) = o1;
    } else if (b < 4096) {
        int u = b - 1024;
        int z = u >> 6, t = u & 63;
        int p = z >> 4, hh = z & 15;
        const float* in = (p == 0 ? wq : p == 1 ? wk : wv) + (size_t)hh * DMODEL * DHEAD;
        u16* out = wqkvT + (size_t)(p * 1024 + hh * 64) * DMODEL;
        transpose_tile32(in, DHEAD, out, DMODEL, (t >> 1) * 32, (t & 1) * 32);
    } else if (b < 5120) {
        int u = b - 4096;
        transpose_tile32(wo, DMODEL, woT, DMODEL, (u >> 5) * 32, (u & 31) * 32);
    } else if (b < 9216) {
        int u = b - 5120;
        transpose_tile32(w1, DFF, w1T, DMODEL, (u >> 7) * 32, (u & 127) * 32);
    } else {
        int u = b - 9216;
        transpose_tile32(w2, DMODEL, w2T, DFF, (u >> 5) * 32, (u & 31) * 32);
    }
}

// ---------------- 8-wave split-KV swapped-operand flash attention ----------
__global__ __launch_bounds__(512) void flash_attn_mfma(
    const u16* __restrict__ qkvb, u16* __restrict__ concatb)
{
    const int bid = blockIdx.x;
    const int lo = bid & 255;
    int it = lo >> 3;
    int h  = lo & 7;
    if (bid >= 256) { it = 31 - it; h += 8; }

    const u16* qh = qkvb + h * DHEAD;
    const u16* kh = qkvb + DMODEL + h * DHEAD;
    const u16* vh = qkvb + 2 * DMODEL + h * DHEAD;
    const int LDQ = 3 * DMODEL;

    __shared__ u16 Ks[4][64][72];
    __shared__ u16 Vt[4][64][72];

    const int tid = threadIdx.x;
    const int l = tid & 63, w = tid >> 6;
    const int grp = w >> 2, wq = w & 3;
    const int fr = l & 15, fg = l >> 4;

    short8 qf[2];
    {
        const u16* qp = qh + (size_t)(it * 64 + wq * 16 + fr) * LDQ + fg * 8;
        qf[0] = *reinterpret_cast<const short8*>(qp);
        qf[1] = *reinterpret_cast<const short8*>(qp + 32);
    }

    const int kr  = tid >> 1;
    const int kb  = kr >> 6, krl = kr & 63;
    const int kc  = (tid & 1) * 32;
    const int vp  = tid >> 2;
    const int vb  = vp >> 5, vpl = vp & 31;
    const int vc  = (tid & 3) * 16;

    short8 kf[4], vf0[2], vf1[2];
    auto PREFETCH = [&](int s) {
        const u16* kg = kh + (size_t)(s * 256 + kr) * LDQ + kc;
        kf[0] = *reinterpret_cast<const short8*>(kg);
        kf[1] = *reinterpret_cast<const short8*>(kg + 8);
        kf[2] = *reinterpret_cast<const short8*>(kg + 16);
        kf[3] = *reinterpret_cast<const short8*>(kg + 24);
        const u16* vg = vh + (size_t)(s * 256 + 2 * vp) * LDQ + vc;
        vf0[0] = *reinterpret_cast<const short8*>(vg);
        vf0[1] = *reinterpret_cast<const short8*>(vg + 8);
        vf1[0] = *reinterpret_cast<const short8*>(vg + LDQ);
        vf1[1] = *reinterpret_cast<const short8*>(vg + LDQ + 8);
    };

    f32x4 o[4];
    #pragma unroll
    for (int n = 0; n < 4; ++n) o[n] = (f32x4){0.f, 0.f, 0.f, 0.f};
    float m_run = -INFINITY, l_run = 0.0f;

    const int sA = fr + 16 * ((2 * fg) & 3);
    const int sB = sA + 16;
    const bool hi = (fg >= 2);

    char* VtSb = (char*)&Vt[vb][0][0];

    const int niter = (it >> 2) + 1;
    PREFETCH(0);

    for (int s = 0; s < niter; ++s) {
        __syncthreads();
        *reinterpret_cast<short8*>(&Ks[kb][krl][kc +  0]) = kf[0];
        *reinterpret_cast<short8*>(&Ks[kb][krl][kc +  8]) = kf[1];
        *reinterpret_cast<short8*>(&Ks[kb][krl][kc + 16]) = kf[2];
        *reinterpret_cast<short8*>(&Ks[kb][krl][kc + 24]) = kf[3];
        #pragma unroll
        for (int c2 = 0; c2 < 2; ++c2) {
            #pragma unroll
            for (int i = 0; i < 8; ++i) {
                u32 word = (u32)(u16)vf0[c2][i] | ((u32)(u16)vf1[c2][i] << 16);
                int dv = vc + c2 * 8 + i;
                int off = 144 * dv + 16 * ((vpl >> 2) ^ ((dv >> 3) & 7)) + 4 * (vpl & 3);
                *reinterpret_cast<u32*>(VtSb + off) = word;
            }
        }
        if (s + 1 < niter) PREFETCH(s + 1);
        __syncthreads();

        #pragma unroll
        for (int t = 0; t < 2; ++t) {
            const int jt = 4 * s + 2 * grp + t;
            if (jt > it) continue;
            const int buf = 2 * grp + t;
            const u16 (*KsG)[72] = Ks[buf];
            char* VtG = (char*)&Vt[buf][0][0];

            f32x4 s_[4];
            #pragma unroll
            for (int n = 0; n < 4; ++n) s_[n] = (f32x4){0.f, 0.f, 0.f, 0.f};
            __builtin_amdgcn_s_setprio(1);
            #pragma unroll
            for (int n = 0; n < 4; ++n) {
                #pragma unroll
                for (int ks = 0; ks < 2; ++ks) {
                    short8 kfrag = *reinterpret_cast<const short8*>(&KsG[n * 16 + fr][ks * 32 + fg * 8]);
                    s_[n] = __builtin_amdgcn_mfma_f32_16x16x32_bf16(kfrag, qf[ks], s_[n], 0, 0, 0);
                }
            }
            __builtin_amdgcn_s_setprio(0);

            const bool diag = (jt == it);
            const int qrow_t = wq * 16 + fr;
            float sv[4][4];
            float pm = -INFINITY;
            #pragma unroll
            for (int n = 0; n < 4; ++n)
                #pragma unroll
                for (int r = 0; r < 4; ++r) {
                    float v = s_[n][r] * 0.125f;
                    if (diag && (n * 16 + fg * 4 + r) > qrow_t) v = -INFINITY;
                    sv[n][r] = v;
                    pm = fmaxf(pm, v);
                }
            pm = fmaxf(pm, __shfl_xor(pm, 16));
            pm = fmaxf(pm, __shfl_xor(pm, 32));
            if (!__all(pm <= m_run + 8.0f)) {
                float mnew = fmaxf(m_run, pm);
                float corr = __expf(m_run - mnew);
                l_run *= corr;
                #pragma unroll
                for (int n = 0; n < 4; ++n) {
                    o[n][0] *= corr; o[n][1] *= corr; o[n][2] *= corr; o[n][3] *= corr;
                }
                m_run = mnew;
            }
            float rs = 0.0f;
            float pp[4][4];
            #pragma unroll
            for (int n = 0; n < 4; ++n)
                #pragma unroll
                for (int r = 0; r < 4; ++r) {
                    float pv = __expf(sv[n][r] - m_run);
                    pp[n][r] = pv;
                    rs += pv;
                }
            rs += __shfl_xor(rs, 16);
            rs += __shfl_xor(rs, 32);
            l_run += rs;

            u32 pk[4][2];
            #pragma unroll
            for (int n = 0; n < 4; ++n) {
                pk[n][0] = (__float_as_uint(pp[n][0]) >> 16) | (__float_as_uint(pp[n][1]) & 0xFFFF0000u);
                pk[n][1] = (__float_as_uint(pp[n][2]) >> 16) | (__float_as_uint(pp[n][3]) & 0xFFFF0000u);
            }

            __builtin_amdgcn_s_setprio(1);
            #pragma unroll
            for (int ks = 0; ks < 2; ++ks) {
                u32 a0 = __shfl(pk[2 * ks][0], sA);
                u32 a1 = __shfl(pk[2 * ks][1], sA);
                u32 a2 = __shfl(pk[2 * ks][0], sB);
                u32 a3 = __shfl(pk[2 * ks][1], sB);
                u32 b0 = __shfl(pk[2 * ks + 1][0], sA);
                u32 b1 = __shfl(pk[2 * ks + 1][1], sA);
                u32 b2 = __shfl(pk[2 * ks + 1][0], sB);
                u32 b3 = __shfl(pk[2 * ks + 1][1], sB);
                union { u32 u[4]; short8 s8; } pb;
                pb.u[0] = hi ? b0 : a0;
                pb.u[1] = hi ? b1 : a1;
                pb.u[2] = hi ? b2 : a2;
                pb.u[3] = hi ? b3 : a3;
                #pragma unroll
                for (int n = 0; n < 4; ++n) {
                    int dv = n * 16 + fr;
                    const short8* vfrag = reinterpret_cast<const short8*>(
                        VtG + 144 * dv + 16 * ((ks * 4 + fg) ^ ((dv >> 3) & 7)));
                    o[n] = __builtin_amdgcn_mfma_f32_16x16x32_bf16(*vfrag, pb.s8, o[n], 0, 0, 0);
                }
            }
            __builtin_amdgcn_s_setprio(0);
        }
    }

    __syncthreads();
    float* mrg = reinterpret_cast<float*>(&Ks[0][0][0]);
    const int slot = (wq * 64 + l) * 18;
    if (grp == 1) {
        #pragma unroll
        for (int n = 0; n < 4; ++n)
            #pragma unroll
            for (int r = 0; r < 4; ++r)
                mrg[slot + n * 4 + r] = o[n][r];
        mrg[slot + 16] = m_run;
        mrg[slot + 17] = l_run;
    }
    __syncthreads();
    if (grp == 0) {
        float mB = mrg[slot + 16], lB = mrg[slot + 17];
        float mstar = fmaxf(m_run, mB);
        float cA = __expf(m_run - mstar);
        float cB = __expf(mB - mstar);
        float inv = 1.0f / (l_run * cA + lB * cB);
        int qrow = it * 64 + wq * 16 + fr;
        #pragma unroll
        for (int n = 0; n < 4; ++n)
            #pragma unroll
            for (int r = 0; r < 4; ++r) {
                float val = (o[n][r] * cA + mrg[slot + n * 4 + r] * cB) * inv;
                concatb[(size_t)qrow * DMODEL + h * DHEAD + n * 16 + fg * 4 + r] = f2b(val);
            }
    }
}

// ---------------- fused fp16-partial-reduce + LayerNorm ----------------
// v = base + (RELUB ? relu(sum(P)+bias2) : sum(P)); out = LN(v)
// OUTF: write fp32 out. DUAL: write bf16 outb. BASEBF16: base is bf16.
template<int NPART, int RELUB, int OUTF, int DUAL, int BASEBF16>
__global__ __launch_bounds__(256) void ln_fuse(
    const f16* __restrict__ P, size_t pstride,
    const void* __restrict__ basev,
    const float* __restrict__ bias2,
    const float* __restrict__ g, const float* __restrict__ b,
    float* __restrict__ out, u16* __restrict__ outb)
{
    int row = blockIdx.x, tid = threadIdx.x;
    __shared__ float red[256];
    size_t off = (size_t)row * DMODEL + tid * 4;

    float a0 = 0.f, a1 = 0.f, a2 = 0.f, a3 = 0.f;
    #pragma unroll
    for (int p = 0; p < NPART; ++p) {
        f16x4 t = *reinterpret_cast<const f16x4*>(P + (size_t)p * pstride + off);
        a0 += (float)t.x; a1 += (float)t.y; a2 += (float)t.z; a3 += (float)t.w;
    }
    if (RELUB) {
        float4 bb = *reinterpret_cast<const float4*>(bias2 + tid * 4);
        a0 = fmaxf(a0 + bb.x, 0.0f); a1 = fmaxf(a1 + bb.y, 0.0f);
        a2 = fmaxf(a2 + bb.z, 0.0f); a3 = fmaxf(a3 + bb.w, 0.0f);
    }
    float vals[4];
    if (BASEBF16) {
        ushort4 bs = *reinterpret_cast<const ushort4*>((const u16*)basev + off);
        vals[0] = a0 + b2f(bs.x); vals[1] = a1 + b2f(bs.y);
        vals[2] = a2 + b2f(bs.z); vals[3] = a3 + b2f(bs.w);
    } else {
        float4 bs = *reinterpret_cast<const float4*>((const float*)basev + off);
        vals[0] = a0 + bs.x; vals[1] = a1 + bs.y; vals[2] = a2 + bs.z; vals[3] = a3 + bs.w;
    }

    float s = vals[0] + vals[1] + vals[2] + vals[3];
    red[tid] = s; __syncthreads();
    for (int st = 128; st > 0; st >>= 1) { if (tid < st) red[tid] += red[tid + st]; __syncthreads(); }
    float mu = red[0] * (1.0f / DMODEL);
    __syncthreads();

    float vs = 0.0f;
    #pragma unroll
    for (int i = 0; i < 4; ++i) { float d = vals[i] - mu; vs += d * d; }
    red[tid] = vs; __syncthreads();
    for (int st = 128; st > 0; st >>= 1) { if (tid < st) red[tid] += red[tid + st]; __syncthreads(); }
    float rstd = rsqrtf(red[0] * (1.0f / DMODEL) + LNEPS);

    float4 gv = *reinterpret_cast<const float4*>(g + tid * 4);
    float4 bv = *reinterpret_cast<const float4*>(b + tid * 4);
    float gs[4] = {gv.x, gv.y, gv.z, gv.w};
    float bsc[4] = {bv.x, bv.y, bv.z, bv.w};
    #pragma unroll
    for (int i = 0; i < 4; ++i) {
        float r = (vals[i] - mu) * rstd * gs[i] + bsc[i];
        if (OUTF) out[off + i] = r;
        if (DUAL) outb[off + i] = f2b(r);
    }
}

// ---------------- launch ----------------
extern "C" void kernel_launch(void* const* d_in, const int* in_sizes, int n_in,
                              void* d_out, int out_size, void* d_ws, size_t ws_size,
                              hipStream_t stream)
{
    const float* x    = (const float*)d_in[0];
    const float* wq   = (const float*)d_in[1];
    const float* wk   = (const float*)d_in[2];
    const float* wv   = (const float*)d_in[3];
    const float* wo   = (const float*)d_in[4];
    const float* ln1g = (const float*)d_in[5];
    const float* ln1b = (const float*)d_in[6];
    const float* w1   = (const float*)d_in[7];
    const float* b1   = (const float*)d_in[8];
    const float* w2   = (const float*)d_in[9];
    const float* b2   = (const float*)d_in[10];
    const float* ln2g = (const float*)d_in[11];
    const float* ln2b = (const float*)d_in[12];
    float* out = (float*)d_out;

    // 64 MB workspace (liveness-checked):
    //  [0,8)   w2T          (prep -> ffn2)
    //  [8,16)  w1T          (prep -> ffn1)
    //  [16,18) woT          (prep -> oproj)
    //  [18,24) wqkvT        (prep -> qkv)
    //  [24,28) xb           (prep -> qkv);   then ff1b [24,40) (ffn1 -> ffn2)
    //  [28,40) qkvb         (qkv -> flash)
    //  [40,44) concatb      (flash -> oproj)
    //  [44,60) Ph fp16 x4   (oproj -> LN1);  then Fh [44,60) (ffn2 -> LN2)
    //  [60,64) h1b          (LN1 -> ffn1, LN2 base)
    char* ws = (char*)d_ws;
    const size_t MB = 1024 * 1024;
    u16* w2T     = (u16*)(ws + 0 * MB);
    u16* w1T     = (u16*)(ws + 8 * MB);
    u16* woT     = (u16*)(ws + 16 * MB);
    u16* wqkvT   = (u16*)(ws + 18 * MB);
    u16* xb      = (u16*)(ws + 24 * MB);
    u16* ff1b    = (u16*)(ws + 24 * MB);
    u16* qkvb    = (u16*)(ws + 28 * MB);
    u16* concatb = (u16*)(ws + 40 * MB);
    f16* Ph      = (f16*)(ws + 44 * MB);   // 4 x 4 MB (oproj partials)
    f16* Fh      = (f16*)(ws + 44 * MB);   // 4 x 4 MB (ffn2 partials)
    u16* h1b     = (u16*)(ws + 60 * MB);

    const size_t PSTRIDE = (size_t)NTOK * DMODEL;   // 2M elements

    dim3 blk(256);

    prep_all<<<dim3(13312), blk, 0, stream>>>(x, wq, wk, wv, wo, w1, w2,
                                              xb, wqkvT, woT, w1T, w2T);

    // qkvb = bf16(xb @ wqkvT^T)
    mfma_gemm<0,0,0,1,1><<<dim3(24, 16), blk, 0, stream>>>(
        xb, DMODEL, wqkvT, DMODEL, qkvb, 3 * DMODEL, DMODEL, nullptr, nullptr, 0, 0);
    flash_attn_mfma<<<dim3(512), dim3(512), 0, stream>>>(qkvb, concatb);
    // oproj split-K=4 -> fp16 partials
    mfma_gemm<0,0,0,0,4><<<dim3(8, 16, 4), blk, 0, stream>>>(
        concatb, DMODEL, woT, DMODEL, Ph, DMODEL, 256, nullptr, nullptr, 0, PSTRIDE);
    // LN1: h1b = bf16(LN(sum(Ph) + x))
    ln_fuse<4,0,0,1,0><<<dim3(NTOK), blk, 0, stream>>>(
        Ph, PSTRIDE, x, nullptr, ln1g, ln1b, nullptr, h1b);
    // ff1 = relu(h1b @ w1T^T + b1) -> bf16
    mfma_gemm<1,1,0,1,1><<<dim3(32, 16), blk, 0, stream>>>(
        h1b, DMODEL, w1T, DMODEL, ff1b, DFF, DMODEL, b1, nullptr, 0, 0);
    // ffn2 split-K=4 -> fp16 partials
    mfma_gemm<0,0,0,0,4><<<dim3(8, 16, 4), blk, 0, stream>>>(
        ff1b, DFF, w2T, DFF, Fh, DMODEL, 1024, nullptr, nullptr, 0, PSTRIDE);
    // LN2: out = LN(h1b + relu(sum(Fh)+b2))
    ln_fuse<4,1,1,0,1><<<dim3(NTOK), blk, 0, stream>>>(
        Fh, PSTRIDE, h1b, b2, ln2g, ln2b, out, nullptr);
}